// Round 14
// baseline (2882.704 us; speedup 1.0000x reference)
//
#include <hip/hip_runtime.h>

typedef _Float16 half8 __attribute__((ext_vector_type(8)));
typedef float f32x4 __attribute__((ext_vector_type(4)));

#define NBLK 256
#define NTHR 512
#define VD   512
#define HM   1024
#define MPAD 144
#define BSENT 129

// HW_REG_XCC_ID (id=20, offset=0, size=4)
#define XCC_ID_IMM 6164

// ---------------- workspace layout ----------------
static constexpr size_t SZ_SWIH = (size_t)4096 * 512 * 2;
static constexpr size_t SZ_W1K  = (size_t)4096 * 1024 * 2;
static constexpr size_t OFF_SWIH = 0;
static constexpr size_t OFF_SWHH = OFF_SWIH + SZ_SWIH;
static constexpr size_t OFF_PWIH = OFF_SWHH + SZ_W1K;
static constexpr size_t OFF_PWHH = OFF_PWIH + SZ_W1K;
static constexpr size_t OFF_BWIH = OFF_PWHH + SZ_W1K;
static constexpr size_t OFF_BWHH = OFF_BWIH + SZ_W1K;
static constexpr size_t OFF_SB   = OFF_BWHH + SZ_W1K;
static constexpr size_t OFF_PB   = OFF_SB + (size_t)4096 * 4;
static constexpr size_t OFF_BB   = OFF_PB + (size_t)4096 * 4;
static constexpr size_t OFF_X16  = OFF_BB + (size_t)4096 * 4;
static constexpr size_t SZ_X16   = (size_t)64 * MPAD * VD * 2;
static constexpr size_t OFF_STATE = OFF_X16 + SZ_X16;
static constexpr size_t OFF_H    = OFF_STATE;               // [2][144][1024] f16
static constexpr size_t SZ_H     = (size_t)2 * MPAD * HM * 2;
static constexpr size_t OFF_HPL  = OFF_H + SZ_H;            // [8 XCD][2][1024] f16
static constexpr size_t SZ_HPL   = (size_t)8 * 2 * HM * 2;
static constexpr size_t OFF_HPG  = OFF_HPL + SZ_HPL;        // [8][1024] f16 gather
static constexpr size_t SZ_HPG   = (size_t)8 * HM * 2;
static constexpr size_t OFF_HB   = OFF_HPG + SZ_HPG;        // [2][1024] f16
static constexpr size_t SZ_HB    = (size_t)2 * HM * 2;
static constexpr size_t OFF_BAR  = OFF_HB + SZ_HB;          // barrier counters (16 KB)
static constexpr size_t STATE_BYTES = (OFF_BAR + 16384) - OFF_STATE;

// bar[] (uint32 idx):
//   census cen[g]=bar[g*16] (g<16); census barrier csub[i]=bar[256+i*16],
//   cmaster=bar[512], cgen=bar[520];
//   per-step local slots: bar[1024+g*64+rank]; per-XCD done: bar[3072+g*16];
//   handoff: hsub[i]=bar[3584+i*16], hmaster=bar[3840], hgen=bar[3848].

// ---------------- helpers ----------------
__device__ __forceinline__ half8 h8z() {
    half8 z = {(_Float16)0,(_Float16)0,(_Float16)0,(_Float16)0,
               (_Float16)0,(_Float16)0,(_Float16)0,(_Float16)0};
    return z;
}

__device__ __forceinline__ half8 ld8(const _Float16* p) {
    return *reinterpret_cast<const half8*>(p);
}

__device__ __forceinline__ void lstm_cell(float ip, float fp, float gp, float op,
                                          float& c, float& h) {
    float ig = 1.0f / (1.0f + expf(-ip));
    float fg = 1.0f / (1.0f + expf(-fp));
    float og = 1.0f / (1.0f + expf(-op));
    float gv = tanhf(gp);
    c = fg * c + ig * gv;
    h = og * tanhf(c);
}

// One-shot global barrier: r5-PROVEN (every thread0 full threadfence + monotone
// counters). Used for census and the para->body handoff.
__device__ __forceinline__ void gsync_global(unsigned* bar, int sub0, int mi,
                                             int gi) {
    __syncthreads();
    if (threadIdx.x == 0) {
        __threadfence();
        unsigned a = __hip_atomic_fetch_add(&bar[sub0 + (blockIdx.x & 15) * 16], 1u,
                                            __ATOMIC_RELAXED, __HIP_MEMORY_SCOPE_AGENT);
        if (a == 15u) {
            unsigned m = __hip_atomic_fetch_add(&bar[mi], 1u,
                                                __ATOMIC_RELAXED, __HIP_MEMORY_SCOPE_AGENT);
            if (m == 15u)
                __hip_atomic_store(&bar[gi], 1u,
                                   __ATOMIC_RELAXED, __HIP_MEMORY_SCOPE_AGENT);
        }
        while (__hip_atomic_load(&bar[gi], __ATOMIC_RELAXED,
                                 __HIP_MEMORY_SCOPE_AGENT) < 1u)
            __builtin_amdgcn_s_sleep(2);
        __threadfence();
    }
    __syncthreads();
}

// XCD-LOCAL per-step barrier = r9's PROVEN gsync5 minus the global phase:
//   non-leader: sc1 slot store; leader: wave-poll slots -> __threadfence()
//   (wbl2+inv on the SHARED XCD L2: publishes all local h, invalidates stale)
//   -> sc1 done-flag; all: poll own XCD's done-flag -> buffer_inv sc0 (L1).
// Identical primitives & ordering to r9 (which passed), just 32 participants.
__device__ __forceinline__ void gsyncX(unsigned* bar, int round, unsigned g,
                                       unsigned rank, unsigned cnt, bool leader) {
    const unsigned tgt = (unsigned)(round + 1);
    __syncthreads();
    if (threadIdx.x < 64) {
        const int lane = threadIdx.x;
        if (leader) {
            for (;;) {
                bool ok = (lane == 0) || (lane >= (int)cnt);
                if (!ok) {
                    unsigned v = __hip_atomic_load(&bar[1024 + g * 64 + lane],
                                                   __ATOMIC_RELAXED,
                                                   __HIP_MEMORY_SCOPE_AGENT);
                    ok = (v >= tgt);
                }
                if (__all(ok)) break;
                __builtin_amdgcn_s_sleep(1);
            }
            __threadfence();               // wbl2+inv on this XCD's L2 (PROVEN)
            if (lane == 0)
                __hip_atomic_store(&bar[3072 + g * 16], tgt,
                                   __ATOMIC_RELAXED, __HIP_MEMORY_SCOPE_AGENT);
        } else {
            if (lane == 0)
                __hip_atomic_store(&bar[1024 + g * 64 + rank], tgt,
                                   __ATOMIC_RELAXED, __HIP_MEMORY_SCOPE_AGENT);
        }
        while (__hip_atomic_load(&bar[3072 + g * 16], __ATOMIC_RELAXED,
                                 __HIP_MEMORY_SCOPE_AGENT) < tgt)
            __builtin_amdgcn_s_sleep(2);
        asm volatile("buffer_inv sc0\n\ts_waitcnt vmcnt(0)" ::: "memory");
    }
    __syncthreads();
}

// ---------------- prep kernels ----------------
__global__ void k_cvt(const float* __restrict__ s, _Float16* __restrict__ d, int n) {
    for (int i = blockIdx.x * blockDim.x + threadIdx.x; i < n; i += gridDim.x * blockDim.x)
        d[i] = (_Float16)s[i];
}

__global__ void k_bias(const float* a1, const float* a2, const float* b1, const float* b2,
                       const float* c1, const float* c2,
                       float* sb, float* pb, float* bb) {
    int i = blockIdx.x * blockDim.x + threadIdx.x;
    if (i < 4096) {
        sb[i] = a1[i] + a2[i];
        pb[i] = b1[i] + b2[i];
        bb[i] = c1[i] + c2[i];
    }
}

// X16[t][row][d]; row 0 = headline, rows 1..128 = body sentences, 129..143 zero pad
__global__ void k_gather(const int* __restrict__ head, const int* __restrict__ body,
                         const float* __restrict__ emb, _Float16* __restrict__ X16) {
    const int total = 64 * MPAD * VD;
    for (int idx = blockIdx.x * blockDim.x + threadIdx.x; idx < total;
         idx += gridDim.x * blockDim.x) {
        int d   = idx & (VD - 1);
        int rt  = idx >> 9;
        int row = rt % MPAD;
        int t   = rt / MPAD;
        float v = 0.0f;
        if (row == 0)         v = emb[(size_t)head[t] * VD + d];
        else if (row < BSENT) v = emb[(size_t)body[(row - 1) * 64 + t] * VD + d];
        X16[idx] = (_Float16)v;
    }
}

// ---------------- main persistent kernel (ROW-SPLIT) ----------------
// XCD p owns sentence rows {1+16p..16+16p} (p=0 also row 0 / headline) and
// computes ALL 1024 hidden units for them -> the recurrence is XCD-LOCAL.
// 32 blocks/XCD (1 per CU, forced by 140KB LDS); block owns 32 hidden units
// (128 gate rows via the r9-proven grow mapping); 8 waves x 4 units each, full
// K per wave. W_hh K-half (131KB) in LDS; rest streams from L3 as MFMA B.
extern "C" __global__ void __launch_bounds__(NTHR, 2)
k_main(const _Float16* __restrict__ sWih, const _Float16* __restrict__ sWhh,
       const _Float16* __restrict__ pWih, const _Float16* __restrict__ pWhh,
       const _Float16* __restrict__ bWih, const _Float16* __restrict__ bWhh,
       const float* __restrict__ sb, const float* __restrict__ pb, const float* __restrict__ bb,
       const _Float16* __restrict__ X16,
       _Float16* H, _Float16* HPL, _Float16* HPG, _Float16* HB,
       float* out, unsigned* bar)
{
    __shared__ half8 wfrag[8192];          // 131 KB: W_hh K 0..511, per-wave cols
    __shared__ float lds[8][16][17];       // 8.7 KB epilogue scratch
    __shared__ unsigned sMeta[4];

    const int tid  = threadIdx.x;
    const int lane = tid & 63;
    const int wv   = tid >> 6;        // 0..7
    const int l15  = lane & 15;
    const int krow = lane >> 4;       // 0..3
    const int rr   = lane >> 2;       // epilogue row 0..15
    const int mm   = lane & 3;        // epilogue unit 0..3

    // ---- census: XCD id, per-XCD rank (leader = rank 0) ----
    {
        unsigned xcc = __builtin_amdgcn_s_getreg(XCC_ID_IMM) & 15u;
        unsigned rk = 0;
        if (tid == 0) {
            rk = __hip_atomic_fetch_add(&bar[xcc * 16], 1u,
                                        __ATOMIC_RELAXED, __HIP_MEMORY_SCOPE_AGENT);
        }
        gsync_global(bar, 256, 512, 520);
        if (tid == 0) {
            sMeta[0] = xcc;
            sMeta[1] = rk;
            sMeta[2] = __hip_atomic_load(&bar[xcc * 16], __ATOMIC_RELAXED,
                                         __HIP_MEMORY_SCOPE_AGENT);
            sMeta[3] = (rk == 0u) ? 1u : 0u;
        }
        __syncthreads();
    }
    const unsigned myG    = sMeta[0];          // 0..7
    const unsigned myRank = sMeta[1];          // 0..31
    const unsigned myCnt  = sMeta[2];          // 32
    const bool     leader = (sMeta[3] != 0u);

    const int unit  = (int)myRank * 32 + wv * 4 + (l15 & 3);   // B-col unit
    const int grow  = (l15 >> 2) * HM + unit;                  // gate row
    const int uo    = (int)myRank * 32 + wv * 4 + mm;          // epilogue unit
    const int RB    = (myG == 0) ? 0 : (1 + 16 * (int)myG);    // row base
    const bool two  = (myG == 0);                              // 2 row-tiles

    const float sbi = sb[uo], sbf = sb[1024 + uo], sbg = sb[2048 + uo], sbo = sb[3072 + uo];
    const float pbi = pb[uo], pbf = pb[1024 + uo], pbg = pb[2048 + uo], pbo = pb[3072 + uo];
    const float bbi = bb[uo], bbf = bb[1024 + uo], bbg = bb[2048 + uo], bbo = bb[3072 + uo];

    // ---- stage W_hh K-tiles 0..15 (K 0..511) for this wave's 16 cols ----
#pragma unroll
    for (int kt = 0; kt < 16; ++kt)
        wfrag[(wv * 16 + kt) * 64 + lane] =
            ld8(sWhh + (size_t)grow * HM + kt * 32 + krow * 8);
    __syncthreads();

    float c0 = 0.f, c1 = 0.f, c_para = 0.f, c_body = 0.f;
    int round = 0;

    const int r0 = RB + l15;          // tile0 A-row
    const int r1 = RB + 16 + l15;     // tile1 A-row (XCD0 only; only row16 valid)

    // ================= sentence LSTM: 64 steps, rows XCD-local =================
#pragma unroll 1
    for (int t = 0; t < 64; ++t) {
        const _Float16* Xt = X16 + (size_t)t * MPAD * VD;
        const _Float16* Hr = H + (size_t)(t & 1) * MPAD * HM;
        _Float16*       Hw = H + (size_t)((t + 1) & 1) * MPAD * HM;

        f32x4 a0 = {0.f,0.f,0.f,0.f}, a1 = {0.f,0.f,0.f,0.f};
        // x-part: K 0..511, B streamed from sWih
#pragma unroll 4
        for (int kt = 0; kt < 16; ++kt) {
            const int kk = kt * 32 + krow * 8;
            half8 b = ld8(sWih + (size_t)grow * VD + kk);
            half8 xa = ld8(Xt + (size_t)r0 * VD + kk);
            a0 = __builtin_amdgcn_mfma_f32_16x16x32_f16(xa, b, a0, 0, 0, 0);
            if (two) {
                half8 xb = ld8(Xt + (size_t)r1 * VD + kk);
                a1 = __builtin_amdgcn_mfma_f32_16x16x32_f16(xb, b, a1, 0, 0, 0);
            }
        }
        // h-part K 0..511: B from LDS
#pragma unroll 4
        for (int kt = 0; kt < 16; ++kt) {
            const int kk = kt * 32 + krow * 8;
            half8 b = wfrag[(wv * 16 + kt) * 64 + lane];
            half8 ha = ld8(Hr + (size_t)r0 * HM + kk);
            a0 = __builtin_amdgcn_mfma_f32_16x16x32_f16(ha, b, a0, 0, 0, 0);
            if (two) {
                half8 hb = ld8(Hr + (size_t)r1 * HM + kk);
                a1 = __builtin_amdgcn_mfma_f32_16x16x32_f16(hb, b, a1, 0, 0, 0);
            }
        }
        // h-part K 512..1023: B streamed from sWhh
#pragma unroll 4
        for (int kt = 16; kt < 32; ++kt) {
            const int kk = kt * 32 + krow * 8;
            half8 b = ld8(sWhh + (size_t)grow * HM + kk);
            half8 ha = ld8(Hr + (size_t)r0 * HM + kk);
            a0 = __builtin_amdgcn_mfma_f32_16x16x32_f16(ha, b, a0, 0, 0, 0);
            if (two) {
                half8 hb = ld8(Hr + (size_t)r1 * HM + kk);
                a1 = __builtin_amdgcn_mfma_f32_16x16x32_f16(hb, b, a1, 0, 0, 0);
            }
        }
        // epilogue tile0 (per-wave stash; same-wave LDS ordered via lgkmcnt)
#pragma unroll
        for (int q = 0; q < 4; ++q) lds[wv][krow * 4 + q][l15] = a0[q];
        asm volatile("s_waitcnt lgkmcnt(0)" ::: "memory");
        {
            const int rowg = RB + rr;           // all 16 valid for every XCD
            float ip = lds[wv][rr][ 0 + mm] + sbi;
            float fp = lds[wv][rr][ 4 + mm] + sbf;
            float gp = lds[wv][rr][ 8 + mm] + sbg;
            float op = lds[wv][rr][12 + mm] + sbo;
            float h;
            lstm_cell(ip, fp, gp, op, c0, h);
            Hw[(size_t)rowg * HM + uo] = (_Float16)h;
            if (t == 63 && myG == 0 && rr == 0) out[1024 + uo] = h;  // r_hidden
        }
        if (two) {      // tile1: only row 16 (rr==0) valid
#pragma unroll
            for (int q = 0; q < 4; ++q) lds[wv][krow * 4 + q][l15] = a1[q];
            asm volatile("s_waitcnt lgkmcnt(0)" ::: "memory");
            if (rr == 0) {
                float ip = lds[wv][0][ 0 + mm] + sbi;
                float fp = lds[wv][0][ 4 + mm] + sbf;
                float gp = lds[wv][0][ 8 + mm] + sbg;
                float op = lds[wv][0][12 + mm] + sbo;
                float h;
                lstm_cell(ip, fp, gp, op, c1, h);
                Hw[(size_t)16 * HM + uo] = (_Float16)h;
            }
        }
        gsyncX(bar, round, myG, myRank, myCnt, leader); ++round;
    }

    // ================= paragraph LSTM: 16 steps, 1 paragraph per XCD =================
    const _Float16* Hfin = H;                       // final sentence h (buf 0)
    _Float16* HPl = HPL + (size_t)myG * 2 * HM;     // XCD-local h_para ping-pong
#pragma unroll 1
    for (int s = 0; s < 16; ++s) {
        const int xrow = 1 + 16 * (int)myG + s;     // sent_h[p=myG][s] (XCD-local)
        f32x4 acc = {0.f,0.f,0.f,0.f};
        // K 0..1023: x = sent encoding; B streamed from pWih
#pragma unroll 4
        for (int kt = 0; kt < 32; ++kt) {
            const int kk = kt * 32 + krow * 8;
            half8 b = ld8(pWih + (size_t)grow * HM + kk);
            half8 a = h8z();
            if (l15 == 0) a = ld8(Hfin + (size_t)xrow * HM + kk);
            acc = __builtin_amdgcn_mfma_f32_16x16x32_f16(a, b, acc, 0, 0, 0);
        }
        // K 0..1023 of h_para: B streamed from pWhh
#pragma unroll 4
        for (int kt = 0; kt < 32; ++kt) {
            const int kk = kt * 32 + krow * 8;
            half8 b = ld8(pWhh + (size_t)grow * HM + kk);
            half8 a = h8z();
            if (l15 == 0) a = ld8(HPl + (size_t)(s & 1) * HM + kk);
            acc = __builtin_amdgcn_mfma_f32_16x16x32_f16(a, b, acc, 0, 0, 0);
        }
#pragma unroll
        for (int q = 0; q < 4; ++q) lds[wv][krow * 4 + q][l15] = acc[q];
        asm volatile("s_waitcnt lgkmcnt(0)" ::: "memory");
        if (rr == 0) {      // lanes 0..3 of each wave: this wave's 4 units
            float ip = lds[wv][0][ 0 + mm] + pbi;
            float fp = lds[wv][0][ 4 + mm] + pbf;
            float gp = lds[wv][0][ 8 + mm] + pbg;
            float op = lds[wv][0][12 + mm] + pbo;
            float h;
            lstm_cell(ip, fp, gp, op, c_para, h);
            HPl[(size_t)((s + 1) & 1) * HM + uo] = (_Float16)h;
            if (s == 15) HPG[(size_t)myG * HM + uo] = (_Float16)h;
        }
        gsyncX(bar, round, myG, myRank, myCnt, leader); ++round;
    }

    // ---- one-time global handoff: h_para[8][1024] -> visible to XCD 0 ----
    gsync_global(bar, 3584, 3840, 3848);
    if (myG != 0) return;

    // ================= body LSTM: 8 steps, XCD 0 only =================
#pragma unroll 1
    for (int t = 0; t < 8; ++t) {
        f32x4 acc = {0.f,0.f,0.f,0.f};
#pragma unroll 4
        for (int kt = 0; kt < 32; ++kt) {
            const int kk = kt * 32 + krow * 8;
            half8 b = ld8(bWih + (size_t)grow * HM + kk);
            half8 a = h8z();
            if (l15 == 0) a = ld8(HPG + (size_t)t * HM + kk);
            acc = __builtin_amdgcn_mfma_f32_16x16x32_f16(a, b, acc, 0, 0, 0);
        }
#pragma unroll 4
        for (int kt = 0; kt < 32; ++kt) {
            const int kk = kt * 32 + krow * 8;
            half8 b = ld8(bWhh + (size_t)grow * HM + kk);
            half8 a = h8z();
            if (l15 == 0) a = ld8(HB + (size_t)(t & 1) * HM + kk);
            acc = __builtin_amdgcn_mfma_f32_16x16x32_f16(a, b, acc, 0, 0, 0);
        }
#pragma unroll
        for (int q = 0; q < 4; ++q) lds[wv][krow * 4 + q][l15] = acc[q];
        asm volatile("s_waitcnt lgkmcnt(0)" ::: "memory");
        if (rr == 0) {
            float ip = lds[wv][0][ 0 + mm] + bbi;
            float fp = lds[wv][0][ 4 + mm] + bbf;
            float gp = lds[wv][0][ 8 + mm] + bbg;
            float op = lds[wv][0][12 + mm] + bbo;
            float h;
            lstm_cell(ip, fp, gp, op, c_body, h);
            HB[(size_t)((t + 1) & 1) * HM + uo] = (_Float16)h;
            if (t == 7) out[uo] = h;               // h_body
        }
        gsyncX(bar, round, myG, myRank, myCnt, leader); ++round;
    }
}

// ---------------- host ----------------
extern "C" void kernel_launch(void* const* d_in, const int* in_sizes, int n_in,
                              void* d_out, int out_size, void* d_ws, size_t ws_size,
                              hipStream_t stream) {
    const int*   head  = (const int*)d_in[0];
    const int*   body  = (const int*)d_in[1];
    const float* emb   = (const float*)d_in[2];
    const float* sWihF = (const float*)d_in[3];
    const float* sWhhF = (const float*)d_in[4];
    const float* sbih  = (const float*)d_in[5];
    const float* sbhh  = (const float*)d_in[6];
    const float* pWihF = (const float*)d_in[7];
    const float* pWhhF = (const float*)d_in[8];
    const float* pbih  = (const float*)d_in[9];
    const float* pbhh  = (const float*)d_in[10];
    const float* bWihF = (const float*)d_in[11];
    const float* bWhhF = (const float*)d_in[12];
    const float* bbih  = (const float*)d_in[13];
    const float* bbhh  = (const float*)d_in[14];

    char* ws = (char*)d_ws;
    _Float16* sWih16 = (_Float16*)(ws + OFF_SWIH);
    _Float16* sWhh16 = (_Float16*)(ws + OFF_SWHH);
    _Float16* pWih16 = (_Float16*)(ws + OFF_PWIH);
    _Float16* pWhh16 = (_Float16*)(ws + OFF_PWHH);
    _Float16* bWih16 = (_Float16*)(ws + OFF_BWIH);
    _Float16* bWhh16 = (_Float16*)(ws + OFF_BWHH);
    float*    sbp    = (float*)(ws + OFF_SB);
    float*    pbp    = (float*)(ws + OFF_PB);
    float*    bbp    = (float*)(ws + OFF_BB);
    _Float16* X16    = (_Float16*)(ws + OFF_X16);
    _Float16* Hp     = (_Float16*)(ws + OFF_H);
    _Float16* HPLp   = (_Float16*)(ws + OFF_HPL);
    _Float16* HPGp   = (_Float16*)(ws + OFF_HPG);
    _Float16* HBp    = (_Float16*)(ws + OFF_HB);
    unsigned* barp   = (unsigned*)(ws + OFF_BAR);
    float*    outp   = (float*)d_out;

    hipMemsetAsync(ws + OFF_STATE, 0, STATE_BYTES, stream);
    k_cvt<<<512, 256, 0, stream>>>(sWihF, sWih16, 4096 * 512);
    k_cvt<<<1024, 256, 0, stream>>>(sWhhF, sWhh16, 4096 * 1024);
    k_cvt<<<1024, 256, 0, stream>>>(pWihF, pWih16, 4096 * 1024);
    k_cvt<<<1024, 256, 0, stream>>>(pWhhF, pWhh16, 4096 * 1024);
    k_cvt<<<1024, 256, 0, stream>>>(bWihF, bWih16, 4096 * 1024);
    k_cvt<<<1024, 256, 0, stream>>>(bWhhF, bWhh16, 4096 * 1024);
    k_bias<<<16, 256, 0, stream>>>(sbih, sbhh, pbih, pbhh, bbih, bbhh, sbp, pbp, bbp);
    k_gather<<<2048, 256, 0, stream>>>(head, body, emb, X16);

    void* args[] = { &sWih16, &sWhh16, &pWih16, &pWhh16, &bWih16, &bWhh16,
                     &sbp, &pbp, &bbp, &X16,
                     &Hp, &HPLp, &HPGp, &HBp, &outp, &barp };
    hipError_t err = hipLaunchCooperativeKernel(reinterpret_cast<void*>(k_main),
                                                dim3(NBLK), dim3(NTHR), args, 0, stream);
    if (err != hipSuccess) {
        k_main<<<NBLK, NTHR, 0, stream>>>(sWih16, sWhh16, pWih16, pWhh16, bWih16, bWhh16,
                                          sbp, pbp, bbp, X16,
                                          Hp, HPLp, HPGp, HBp, outp, barp);
    }
}

// Round 15
// 2802.505 us; speedup vs baseline: 1.0286x; 1.0286x over previous
//
#include <hip/hip_runtime.h>

typedef _Float16 half8 __attribute__((ext_vector_type(8)));
typedef float f32x4 __attribute__((ext_vector_type(4)));

#define NBLK 256
#define NTHR 512
#define VD   512
#define HM   1024
#define MPAD 144
#define BSENT 129

// HW_REG_XCC_ID (id=20, offset=0, size=4)
#define XCC_ID_IMM 6164

// ---------------- workspace layout ----------------
static constexpr size_t SZ_SWIH = (size_t)4096 * 512 * 2;
static constexpr size_t SZ_W1K  = (size_t)4096 * 1024 * 2;
static constexpr size_t OFF_SWIH = 0;
static constexpr size_t OFF_SWHH = OFF_SWIH + SZ_SWIH;
static constexpr size_t OFF_PWIH = OFF_SWHH + SZ_W1K;
static constexpr size_t OFF_PWHH = OFF_PWIH + SZ_W1K;
static constexpr size_t OFF_BWIH = OFF_PWHH + SZ_W1K;
static constexpr size_t OFF_BWHH = OFF_BWIH + SZ_W1K;
static constexpr size_t OFF_SB   = OFF_BWHH + SZ_W1K;
static constexpr size_t OFF_PB   = OFF_SB + (size_t)4096 * 4;
static constexpr size_t OFF_BB   = OFF_PB + (size_t)4096 * 4;
static constexpr size_t OFF_X16  = OFF_BB + (size_t)4096 * 4;
static constexpr size_t SZ_X16   = (size_t)64 * MPAD * VD * 2;
static constexpr size_t OFF_STATE = OFF_X16 + SZ_X16;
static constexpr size_t OFF_H    = OFF_STATE;               // [2][144][1024] f16
static constexpr size_t SZ_H     = (size_t)2 * MPAD * HM * 2;
static constexpr size_t OFF_HPL  = OFF_H + SZ_H;            // [8 XCD][2][1024] f16
static constexpr size_t SZ_HPL   = (size_t)8 * 2 * HM * 2;
static constexpr size_t OFF_HPG  = OFF_HPL + SZ_HPL;        // [8][1024] f16 gather
static constexpr size_t SZ_HPG   = (size_t)8 * HM * 2;
static constexpr size_t OFF_HB   = OFF_HPG + SZ_HPG;        // [2][1024] f16
static constexpr size_t SZ_HB    = (size_t)2 * HM * 2;
static constexpr size_t OFF_BAR  = OFF_HB + SZ_HB;          // barrier counters (16 KB)
static constexpr size_t STATE_BYTES = (OFF_BAR + 16384) - OFF_STATE;

// bar[] (uint32 idx):
//   census cen[g]=bar[g*16] (g<16); census barrier csub[i]=bar[256+i*16],
//   cmaster=bar[512], cgen=bar[520];
//   per-step local slots: bar[1024+g*64+rank]; per-XCD done: bar[3072+g*16];
//   handoff: hsub[i]=bar[3584+i*16], hmaster=bar[3840], hgen=bar[3848].

// ---------------- helpers ----------------
__device__ __forceinline__ half8 h8z() {
    half8 z = {(_Float16)0,(_Float16)0,(_Float16)0,(_Float16)0,
               (_Float16)0,(_Float16)0,(_Float16)0,(_Float16)0};
    return z;
}

__device__ __forceinline__ half8 ld8(const _Float16* p) {
    return *reinterpret_cast<const half8*>(p);
}

__device__ __forceinline__ void lstm_cell(float ip, float fp, float gp, float op,
                                          float& c, float& h) {
    float ig = 1.0f / (1.0f + expf(-ip));
    float fg = 1.0f / (1.0f + expf(-fp));
    float og = 1.0f / (1.0f + expf(-op));
    float gv = tanhf(gp);
    c = fg * c + ig * gv;
    h = og * tanhf(c);
}

// One-shot global barrier: r5-PROVEN (every thread0 full threadfence + monotone
// counters). Used for census and the para->body handoff (flushes each producer
// XCD's L2 to L3 so XCD 0 can read HPG).
__device__ __forceinline__ void gsync_global(unsigned* bar, int sub0, int mi,
                                             int gi) {
    __syncthreads();
    if (threadIdx.x == 0) {
        __threadfence();
        unsigned a = __hip_atomic_fetch_add(&bar[sub0 + (blockIdx.x & 15) * 16], 1u,
                                            __ATOMIC_RELAXED, __HIP_MEMORY_SCOPE_AGENT);
        if (a == 15u) {
            unsigned m = __hip_atomic_fetch_add(&bar[mi], 1u,
                                                __ATOMIC_RELAXED, __HIP_MEMORY_SCOPE_AGENT);
            if (m == 15u)
                __hip_atomic_store(&bar[gi], 1u,
                                   __ATOMIC_RELAXED, __HIP_MEMORY_SCOPE_AGENT);
        }
        while (__hip_atomic_load(&bar[gi], __ATOMIC_RELAXED,
                                 __HIP_MEMORY_SCOPE_AGENT) < 1u)
            __builtin_amdgcn_s_sleep(2);
        __threadfence();
    }
    __syncthreads();
}

// XCD-LOCAL per-step barrier, NO FENCE (round-15 change):
// In the row-split, h producers and consumers share ONE XCD -> the shared L2
// IS their coherence point. Plain h stores are write-through from L1 and
// committed to the shared L2 by the entry __syncthreads' vmcnt(0) drain,
// BEFORE the sc1 slot store issues. Consumers' only staleness hazard is
// their own L1 (2-deep ping-pong re-reads) -> buffer_inv sc0 (proven).
// The r14 __threadfence here (wbl2+inv) was needed only for cross-XCD h in
// the column-split; in row-split it only served to wipe the weight cache
// (FETCH_SIZE 3.24 GB). Signaling (sc1 slots + done flag) unchanged/proven.
__device__ __forceinline__ void gsyncX(unsigned* bar, int round, unsigned g,
                                       unsigned rank, unsigned cnt, bool leader) {
    const unsigned tgt = (unsigned)(round + 1);
    __syncthreads();
    if (threadIdx.x < 64) {
        const int lane = threadIdx.x;
        if (leader) {
            for (;;) {
                bool ok = (lane == 0) || (lane >= (int)cnt);
                if (!ok) {
                    unsigned v = __hip_atomic_load(&bar[1024 + g * 64 + lane],
                                                   __ATOMIC_RELAXED,
                                                   __HIP_MEMORY_SCOPE_AGENT);
                    ok = (v >= tgt);
                }
                if (__all(ok)) break;
                __builtin_amdgcn_s_sleep(1);
            }
            if (lane == 0)
                __hip_atomic_store(&bar[3072 + g * 16], tgt,
                                   __ATOMIC_RELAXED, __HIP_MEMORY_SCOPE_AGENT);
        } else {
            if (lane == 0)
                __hip_atomic_store(&bar[1024 + g * 64 + rank], tgt,
                                   __ATOMIC_RELAXED, __HIP_MEMORY_SCOPE_AGENT);
        }
        while (__hip_atomic_load(&bar[3072 + g * 16], __ATOMIC_RELAXED,
                                 __HIP_MEMORY_SCOPE_AGENT) < tgt)
            __builtin_amdgcn_s_sleep(2);
        asm volatile("buffer_inv sc0\n\ts_waitcnt vmcnt(0)" ::: "memory");
    }
    __syncthreads();
}

// ---------------- prep kernels ----------------
__global__ void k_cvt(const float* __restrict__ s, _Float16* __restrict__ d, int n) {
    for (int i = blockIdx.x * blockDim.x + threadIdx.x; i < n; i += gridDim.x * blockDim.x)
        d[i] = (_Float16)s[i];
}

__global__ void k_bias(const float* a1, const float* a2, const float* b1, const float* b2,
                       const float* c1, const float* c2,
                       float* sb, float* pb, float* bb) {
    int i = blockIdx.x * blockDim.x + threadIdx.x;
    if (i < 4096) {
        sb[i] = a1[i] + a2[i];
        pb[i] = b1[i] + b2[i];
        bb[i] = c1[i] + c2[i];
    }
}

// X16[t][row][d]; row 0 = headline, rows 1..128 = body sentences, 129..143 zero pad
__global__ void k_gather(const int* __restrict__ head, const int* __restrict__ body,
                         const float* __restrict__ emb, _Float16* __restrict__ X16) {
    const int total = 64 * MPAD * VD;
    for (int idx = blockIdx.x * blockDim.x + threadIdx.x; idx < total;
         idx += gridDim.x * blockDim.x) {
        int d   = idx & (VD - 1);
        int rt  = idx >> 9;
        int row = rt % MPAD;
        int t   = rt / MPAD;
        float v = 0.0f;
        if (row == 0)         v = emb[(size_t)head[t] * VD + d];
        else if (row < BSENT) v = emb[(size_t)body[(row - 1) * 64 + t] * VD + d];
        X16[idx] = (_Float16)v;
    }
}

// ---------------- main persistent kernel (ROW-SPLIT, fence-free steps) ----------------
// XCD p owns sentence rows {1+16p..16+16p} (p=0 also row 0) and computes ALL
// 1024 hidden units for them -> recurrence is XCD-LOCAL (shared-L2 coherent).
// 32 blocks/XCD; block owns 32 hidden units (128 gate rows); 8 waves x 4 units.
// W_hh K 0..511 in LDS (131 KB); remaining weights stream via the now-stable
// L2 (no per-step invalidate) with L3 backing.
extern "C" __global__ void __launch_bounds__(NTHR, 2)
k_main(const _Float16* __restrict__ sWih, const _Float16* __restrict__ sWhh,
       const _Float16* __restrict__ pWih, const _Float16* __restrict__ pWhh,
       const _Float16* __restrict__ bWih, const _Float16* __restrict__ bWhh,
       const float* __restrict__ sb, const float* __restrict__ pb, const float* __restrict__ bb,
       const _Float16* __restrict__ X16,
       _Float16* H, _Float16* HPL, _Float16* HPG, _Float16* HB,
       float* out, unsigned* bar)
{
    __shared__ half8 wfrag[8192];          // 131 KB weight fragments
    __shared__ float lds[8][16][17];       // 8.7 KB epilogue scratch
    __shared__ unsigned sMeta[4];

    const int tid  = threadIdx.x;
    const int lane = tid & 63;
    const int wv   = tid >> 6;        // 0..7
    const int l15  = lane & 15;
    const int krow = lane >> 4;       // 0..3
    const int rr   = lane >> 2;       // epilogue row 0..15
    const int mm   = lane & 3;        // epilogue unit 0..3

    // ---- census: XCD id, per-XCD rank (leader = rank 0) ----
    {
        unsigned xcc = __builtin_amdgcn_s_getreg(XCC_ID_IMM) & 15u;
        unsigned rk = 0;
        if (tid == 0) {
            rk = __hip_atomic_fetch_add(&bar[xcc * 16], 1u,
                                        __ATOMIC_RELAXED, __HIP_MEMORY_SCOPE_AGENT);
        }
        gsync_global(bar, 256, 512, 520);
        if (tid == 0) {
            sMeta[0] = xcc;
            sMeta[1] = rk;
            sMeta[2] = __hip_atomic_load(&bar[xcc * 16], __ATOMIC_RELAXED,
                                         __HIP_MEMORY_SCOPE_AGENT);
            sMeta[3] = (rk == 0u) ? 1u : 0u;
        }
        __syncthreads();
    }
    const unsigned myG    = sMeta[0];          // 0..7
    const unsigned myRank = sMeta[1];          // 0..31
    const unsigned myCnt  = sMeta[2];          // 32
    const bool     leader = (sMeta[3] != 0u);

    const int unit  = (int)myRank * 32 + wv * 4 + (l15 & 3);   // B-col unit
    const int grow  = (l15 >> 2) * HM + unit;                  // gate row
    const int uo    = (int)myRank * 32 + wv * 4 + mm;          // epilogue unit
    const int RB    = (myG == 0) ? 0 : (1 + 16 * (int)myG);    // row base
    const bool two  = (myG == 0);                              // 2 row-tiles

    const float sbi = sb[uo], sbf = sb[1024 + uo], sbg = sb[2048 + uo], sbo = sb[3072 + uo];
    const float pbi = pb[uo], pbf = pb[1024 + uo], pbg = pb[2048 + uo], pbo = pb[3072 + uo];
    const float bbi = bb[uo], bbf = bb[1024 + uo], bbg = bb[2048 + uo], bbo = bb[3072 + uo];

    // ---- stage W_hh K-tiles 0..15 (K 0..511) for this wave's 16 cols ----
#pragma unroll
    for (int kt = 0; kt < 16; ++kt)
        wfrag[(wv * 16 + kt) * 64 + lane] =
            ld8(sWhh + (size_t)grow * HM + kt * 32 + krow * 8);
    __syncthreads();

    float c0 = 0.f, c1 = 0.f, c_para = 0.f, c_body = 0.f;
    int round = 0;

    const int r0 = RB + l15;          // tile0 A-row
    const int r1 = RB + 16 + l15;     // tile1 A-row (XCD0 only; only row16 valid)

    // ================= sentence LSTM: 64 steps, rows XCD-local =================
#pragma unroll 1
    for (int t = 0; t < 64; ++t) {
        const _Float16* Xt = X16 + (size_t)t * MPAD * VD;
        const _Float16* Hr = H + (size_t)(t & 1) * MPAD * HM;
        _Float16*       Hw = H + (size_t)((t + 1) & 1) * MPAD * HM;

        f32x4 a0 = {0.f,0.f,0.f,0.f}, a1 = {0.f,0.f,0.f,0.f};
        // x-part: K 0..511, B streamed from sWih (L2-cached now)
#pragma unroll 4
        for (int kt = 0; kt < 16; ++kt) {
            const int kk = kt * 32 + krow * 8;
            half8 b = ld8(sWih + (size_t)grow * VD + kk);
            half8 xa = ld8(Xt + (size_t)r0 * VD + kk);
            a0 = __builtin_amdgcn_mfma_f32_16x16x32_f16(xa, b, a0, 0, 0, 0);
            if (two) {
                half8 xb = ld8(Xt + (size_t)r1 * VD + kk);
                a1 = __builtin_amdgcn_mfma_f32_16x16x32_f16(xb, b, a1, 0, 0, 0);
            }
        }
        // h-part K 0..511: B from LDS
#pragma unroll 4
        for (int kt = 0; kt < 16; ++kt) {
            const int kk = kt * 32 + krow * 8;
            half8 b = wfrag[(wv * 16 + kt) * 64 + lane];
            half8 ha = ld8(Hr + (size_t)r0 * HM + kk);
            a0 = __builtin_amdgcn_mfma_f32_16x16x32_f16(ha, b, a0, 0, 0, 0);
            if (two) {
                half8 hb = ld8(Hr + (size_t)r1 * HM + kk);
                a1 = __builtin_amdgcn_mfma_f32_16x16x32_f16(hb, b, a1, 0, 0, 0);
            }
        }
        // h-part K 512..1023: B streamed from sWhh (L2-cached now)
#pragma unroll 4
        for (int kt = 16; kt < 32; ++kt) {
            const int kk = kt * 32 + krow * 8;
            half8 b = ld8(sWhh + (size_t)grow * HM + kk);
            half8 ha = ld8(Hr + (size_t)r0 * HM + kk);
            a0 = __builtin_amdgcn_mfma_f32_16x16x32_f16(ha, b, a0, 0, 0, 0);
            if (two) {
                half8 hb = ld8(Hr + (size_t)r1 * HM + kk);
                a1 = __builtin_amdgcn_mfma_f32_16x16x32_f16(hb, b, a1, 0, 0, 0);
            }
        }
        // epilogue tile0 (per-wave stash; same-wave LDS ordered via lgkmcnt)
#pragma unroll
        for (int q = 0; q < 4; ++q) lds[wv][krow * 4 + q][l15] = a0[q];
        asm volatile("s_waitcnt lgkmcnt(0)" ::: "memory");
        {
            const int rowg = RB + rr;
            float ip = lds[wv][rr][ 0 + mm] + sbi;
            float fp = lds[wv][rr][ 4 + mm] + sbf;
            float gp = lds[wv][rr][ 8 + mm] + sbg;
            float op = lds[wv][rr][12 + mm] + sbo;
            float h;
            lstm_cell(ip, fp, gp, op, c0, h);
            Hw[(size_t)rowg * HM + uo] = (_Float16)h;
            if (t == 63 && myG == 0 && rr == 0) out[1024 + uo] = h;  // r_hidden
        }
        if (two) {      // tile1: only row 16 (rr==0) valid
#pragma unroll
            for (int q = 0; q < 4; ++q) lds[wv][krow * 4 + q][l15] = a1[q];
            asm volatile("s_waitcnt lgkmcnt(0)" ::: "memory");
            if (rr == 0) {
                float ip = lds[wv][0][ 0 + mm] + sbi;
                float fp = lds[wv][0][ 4 + mm] + sbf;
                float gp = lds[wv][0][ 8 + mm] + sbg;
                float op = lds[wv][0][12 + mm] + sbo;
                float h;
                lstm_cell(ip, fp, gp, op, c1, h);
                Hw[(size_t)16 * HM + uo] = (_Float16)h;
            }
        }
        gsyncX(bar, round, myG, myRank, myCnt, leader); ++round;
    }

    // ---- restage wfrag with pWih K-tiles 0..15 for the paragraph stage ----
    __syncthreads();
#pragma unroll
    for (int kt = 0; kt < 16; ++kt)
        wfrag[(wv * 16 + kt) * 64 + lane] =
            ld8(pWih + (size_t)grow * HM + kt * 32 + krow * 8);
    __syncthreads();

    // ================= paragraph LSTM: 16 steps, 1 paragraph per XCD =================
    const _Float16* Hfin = H;                       // final sentence h (buf 0)
    _Float16* HPl = HPL + (size_t)myG * 2 * HM;     // XCD-local h_para ping-pong
#pragma unroll 1
    for (int s = 0; s < 16; ++s) {
        const int xrow = 1 + 16 * (int)myG + s;     // sent_h[p=myG][s] (XCD-local)
        f32x4 acc = {0.f,0.f,0.f,0.f};
        // x = sent encoding; pWih K 0..511 from LDS, 512..1023 streamed
#pragma unroll 4
        for (int kt = 0; kt < 16; ++kt) {
            const int kk = kt * 32 + krow * 8;
            half8 b = wfrag[(wv * 16 + kt) * 64 + lane];
            half8 a = h8z();
            if (l15 == 0) a = ld8(Hfin + (size_t)xrow * HM + kk);
            acc = __builtin_amdgcn_mfma_f32_16x16x32_f16(a, b, acc, 0, 0, 0);
        }
#pragma unroll 4
        for (int kt = 16; kt < 32; ++kt) {
            const int kk = kt * 32 + krow * 8;
            half8 b = ld8(pWih + (size_t)grow * HM + kk);
            half8 a = h8z();
            if (l15 == 0) a = ld8(Hfin + (size_t)xrow * HM + kk);
            acc = __builtin_amdgcn_mfma_f32_16x16x32_f16(a, b, acc, 0, 0, 0);
        }
        // h_para part: pWhh streamed
#pragma unroll 4
        for (int kt = 0; kt < 32; ++kt) {
            const int kk = kt * 32 + krow * 8;
            half8 b = ld8(pWhh + (size_t)grow * HM + kk);
            half8 a = h8z();
            if (l15 == 0) a = ld8(HPl + (size_t)(s & 1) * HM + kk);
            acc = __builtin_amdgcn_mfma_f32_16x16x32_f16(a, b, acc, 0, 0, 0);
        }
#pragma unroll
        for (int q = 0; q < 4; ++q) lds[wv][krow * 4 + q][l15] = acc[q];
        asm volatile("s_waitcnt lgkmcnt(0)" ::: "memory");
        if (rr == 0) {      // lanes 0..3 of each wave: this wave's 4 units
            float ip = lds[wv][0][ 0 + mm] + pbi;
            float fp = lds[wv][0][ 4 + mm] + pbf;
            float gp = lds[wv][0][ 8 + mm] + pbg;
            float op = lds[wv][0][12 + mm] + pbo;
            float h;
            lstm_cell(ip, fp, gp, op, c_para, h);
            HPl[(size_t)((s + 1) & 1) * HM + uo] = (_Float16)h;
            if (s == 15) HPG[(size_t)myG * HM + uo] = (_Float16)h;
        }
        gsyncX(bar, round, myG, myRank, myCnt, leader); ++round;
    }

    // ---- one-time global handoff: h_para[8][1024] -> visible to XCD 0 ----
    gsync_global(bar, 3584, 3840, 3848);
    if (myG != 0) return;

    // ================= body LSTM: 8 steps, XCD 0 only =================
#pragma unroll 1
    for (int t = 0; t < 8; ++t) {
        f32x4 acc = {0.f,0.f,0.f,0.f};
#pragma unroll 4
        for (int kt = 0; kt < 32; ++kt) {
            const int kk = kt * 32 + krow * 8;
            half8 b = ld8(bWih + (size_t)grow * HM + kk);
            half8 a = h8z();
            if (l15 == 0) a = ld8(HPG + (size_t)t * HM + kk);
            acc = __builtin_amdgcn_mfma_f32_16x16x32_f16(a, b, acc, 0, 0, 0);
        }
#pragma unroll 4
        for (int kt = 0; kt < 32; ++kt) {
            const int kk = kt * 32 + krow * 8;
            half8 b = ld8(bWhh + (size_t)grow * HM + kk);
            half8 a = h8z();
            if (l15 == 0) a = ld8(HB + (size_t)(t & 1) * HM + kk);
            acc = __builtin_amdgcn_mfma_f32_16x16x32_f16(a, b, acc, 0, 0, 0);
        }
#pragma unroll
        for (int q = 0; q < 4; ++q) lds[wv][krow * 4 + q][l15] = acc[q];
        asm volatile("s_waitcnt lgkmcnt(0)" ::: "memory");
        if (rr == 0) {
            float ip = lds[wv][0][ 0 + mm] + bbi;
            float fp = lds[wv][0][ 4 + mm] + bbf;
            float gp = lds[wv][0][ 8 + mm] + bbg;
            float op = lds[wv][0][12 + mm] + bbo;
            float h;
            lstm_cell(ip, fp, gp, op, c_body, h);
            HB[(size_t)((t + 1) & 1) * HM + uo] = (_Float16)h;
            if (t == 7) out[uo] = h;               // h_body
        }
        gsyncX(bar, round, myG, myRank, myCnt, leader); ++round;
    }
}

// ---------------- host ----------------
extern "C" void kernel_launch(void* const* d_in, const int* in_sizes, int n_in,
                              void* d_out, int out_size, void* d_ws, size_t ws_size,
                              hipStream_t stream) {
    const int*   head  = (const int*)d_in[0];
    const int*   body  = (const int*)d_in[1];
    const float* emb   = (const float*)d_in[2];
    const float* sWihF = (const float*)d_in[3];
    const float* sWhhF = (const float*)d_in[4];
    const float* sbih  = (const float*)d_in[5];
    const float* sbhh  = (const float*)d_in[6];
    const float* pWihF = (const float*)d_in[7];
    const float* pWhhF = (const float*)d_in[8];
    const float* pbih  = (const float*)d_in[9];
    const float* pbhh  = (const float*)d_in[10];
    const float* bWihF = (const float*)d_in[11];
    const float* bWhhF = (const float*)d_in[12];
    const float* bbih  = (const float*)d_in[13];
    const float* bbhh  = (const float*)d_in[14];

    char* ws = (char*)d_ws;
    _Float16* sWih16 = (_Float16*)(ws + OFF_SWIH);
    _Float16* sWhh16 = (_Float16*)(ws + OFF_SWHH);
    _Float16* pWih16 = (_Float16*)(ws + OFF_PWIH);
    _Float16* pWhh16 = (_Float16*)(ws + OFF_PWHH);
    _Float16* bWih16 = (_Float16*)(ws + OFF_BWIH);
    _Float16* bWhh16 = (_Float16*)(ws + OFF_BWHH);
    float*    sbp    = (float*)(ws + OFF_SB);
    float*    pbp    = (float*)(ws + OFF_PB);
    float*    bbp    = (float*)(ws + OFF_BB);
    _Float16* X16    = (_Float16*)(ws + OFF_X16);
    _Float16* Hp     = (_Float16*)(ws + OFF_H);
    _Float16* HPLp   = (_Float16*)(ws + OFF_HPL);
    _Float16* HPGp   = (_Float16*)(ws + OFF_HPG);
    _Float16* HBp    = (_Float16*)(ws + OFF_HB);
    unsigned* barp   = (unsigned*)(ws + OFF_BAR);
    float*    outp   = (float*)d_out;

    hipMemsetAsync(ws + OFF_STATE, 0, STATE_BYTES, stream);
    k_cvt<<<512, 256, 0, stream>>>(sWihF, sWih16, 4096 * 512);
    k_cvt<<<1024, 256, 0, stream>>>(sWhhF, sWhh16, 4096 * 1024);
    k_cvt<<<1024, 256, 0, stream>>>(pWihF, pWih16, 4096 * 1024);
    k_cvt<<<1024, 256, 0, stream>>>(pWhhF, pWhh16, 4096 * 1024);
    k_cvt<<<1024, 256, 0, stream>>>(bWihF, bWih16, 4096 * 1024);
    k_cvt<<<1024, 256, 0, stream>>>(bWhhF, bWhh16, 4096 * 1024);
    k_bias<<<16, 256, 0, stream>>>(sbih, sbhh, pbih, pbhh, bbih, bbhh, sbp, pbp, bbp);
    k_gather<<<2048, 256, 0, stream>>>(head, body, emb, X16);

    void* args[] = { &sWih16, &sWhh16, &pWih16, &pWhh16, &bWih16, &bWhh16,
                     &sbp, &pbp, &bbp, &X16,
                     &Hp, &HPLp, &HPGp, &HBp, &outp, &barp };
    hipError_t err = hipLaunchCooperativeKernel(reinterpret_cast<void*>(k_main),
                                                dim3(NBLK), dim3(NTHR), args, 0, stream);
    if (err != hipSuccess) {
        k_main<<<NBLK, NTHR, 0, stream>>>(sWih16, sWhh16, pWih16, pWhh16, bWih16, bWhh16,
                                          sbp, pbp, bbp, X16,
                                          Hp, HPLp, HPGp, HBp, outp, barp);
    }
}

// Round 16
// 2466.423 us; speedup vs baseline: 1.1688x; 1.1363x over previous
//
#include <hip/hip_runtime.h>

typedef _Float16 half8 __attribute__((ext_vector_type(8)));
typedef float f32x4 __attribute__((ext_vector_type(4)));

#define NBLK 256
#define NTHR 512
#define VD   512
#define HM   1024
#define NROW 129      // valid rows 0..128

// HW_REG_XCC_ID (id=20, offset=0, size=4)
#define XCC_ID_IMM 6164

// ---------------- workspace layout (~56.4 MB, <= r1-proven ~57) ----------------
static constexpr size_t SZ_SWIH = (size_t)4096 * 512 * 2;
static constexpr size_t SZ_W1K  = (size_t)4096 * 1024 * 2;
static constexpr size_t OFF_SWIH = 0;
static constexpr size_t OFF_SWHH = OFF_SWIH + SZ_SWIH;
static constexpr size_t OFF_PWIH = OFF_SWHH + SZ_W1K;
static constexpr size_t OFF_PWHH = OFF_PWIH + SZ_W1K;
static constexpr size_t OFF_BWIH = OFF_PWHH + SZ_W1K;
static constexpr size_t OFF_BWHH = OFF_BWIH + SZ_W1K;
static constexpr size_t OFF_SB   = OFF_BWHH + SZ_W1K;
static constexpr size_t OFF_PB   = OFF_SB + (size_t)4096 * 4;
static constexpr size_t OFF_BB   = OFF_PB + (size_t)4096 * 4;
static constexpr size_t OFF_XPRE = OFF_BB + (size_t)4096 * 4;          // [8][129][4096] f16
static constexpr size_t SZ_XPRE  = (size_t)8 * NROW * 4096 * 2;
static constexpr size_t OFF_PPRE = OFF_XPRE + SZ_XPRE;                 // [16][8][4096] f16
static constexpr size_t SZ_PPRE  = (size_t)16 * 8 * 4096 * 2;
static constexpr size_t OFF_BPRE = OFF_PPRE + SZ_PPRE;                 // [8][4096] f16
static constexpr size_t SZ_BPRE  = (size_t)8 * 4096 * 2;
static constexpr size_t OFF_STATE = OFF_BPRE + SZ_BPRE;
static constexpr size_t OFF_H    = OFF_STATE;                          // [2][144][1024] f16
static constexpr size_t SZ_H     = (size_t)2 * 144 * HM * 2;
static constexpr size_t OFF_HPL  = OFF_H + SZ_H;                       // [8][2][1024] f16
static constexpr size_t SZ_HPL   = (size_t)8 * 2 * HM * 2;
static constexpr size_t OFF_HPG  = OFF_HPL + SZ_HPL;                   // [8][1024] f16
static constexpr size_t SZ_HPG   = (size_t)8 * HM * 2;
static constexpr size_t OFF_HB   = OFF_HPG + SZ_HPG;                   // [2][1024] f16
static constexpr size_t SZ_HB    = (size_t)2 * HM * 2;
static constexpr size_t OFF_BAR  = OFF_HB + SZ_HB;                     // 16 KB counters
static constexpr size_t STATE_BYTES = (OFF_BAR + 16384) - OFF_STATE;

// bar[] (uint32 idx): census cen[g]=bar[g*16]; census barrier csub[i]=bar[256+i*16],
// cmaster=bar[512], cgen=bar[520]; local slots bar[1024+g*64+rank]; per-XCD done
// bar[3072+g*16]; handoff hsub[i]=bar[3584+i*16], hmaster=bar[3840], hgen=bar[3848].

// ---------------- helpers ----------------
__device__ __forceinline__ half8 h8z() {
    half8 z = {(_Float16)0,(_Float16)0,(_Float16)0,(_Float16)0,
               (_Float16)0,(_Float16)0,(_Float16)0,(_Float16)0};
    return z;
}

__device__ __forceinline__ half8 ld8(const _Float16* p) {
    return *reinterpret_cast<const half8*>(p);
}

// load 8 fp32 and convert to half8 (for direct-from-emb A fragments)
__device__ __forceinline__ half8 ld8_cvt(const float* p) {
    half8 r;
#pragma unroll
    for (int j = 0; j < 8; ++j) r[j] = (_Float16)p[j];
    return r;
}

__device__ __forceinline__ void lstm_cell(float ip, float fp, float gp, float op,
                                          float& c, float& h) {
    float ig = 1.0f / (1.0f + expf(-ip));
    float fg = 1.0f / (1.0f + expf(-fp));
    float og = 1.0f / (1.0f + expf(-op));
    float gv = tanhf(gp);
    c = fg * c + ig * gv;
    h = og * tanhf(c);
}

// One-shot global barrier (r5-PROVEN): full threadfence on every block's thread0.
__device__ __forceinline__ void gsync_global(unsigned* bar, int sub0, int mi, int gi) {
    __syncthreads();
    if (threadIdx.x == 0) {
        __threadfence();
        unsigned a = __hip_atomic_fetch_add(&bar[sub0 + (blockIdx.x & 15) * 16], 1u,
                                            __ATOMIC_RELAXED, __HIP_MEMORY_SCOPE_AGENT);
        if (a == 15u) {
            unsigned m = __hip_atomic_fetch_add(&bar[mi], 1u,
                                                __ATOMIC_RELAXED, __HIP_MEMORY_SCOPE_AGENT);
            if (m == 15u)
                __hip_atomic_store(&bar[gi], 1u,
                                   __ATOMIC_RELAXED, __HIP_MEMORY_SCOPE_AGENT);
        }
        while (__hip_atomic_load(&bar[gi], __ATOMIC_RELAXED,
                                 __HIP_MEMORY_SCOPE_AGENT) < 1u)
            __builtin_amdgcn_s_sleep(2);
        __threadfence();
    }
    __syncthreads();
}

// XCD-local fence-free barrier (r15-PROVEN verbatim): entry __syncthreads drains
// all waves' plain stores into the shared XCD L2 (the coherence point for the
// row-split); sc1 slot/done signaling; exit per-CU L1 invalidate.
__device__ __forceinline__ void gsyncX(unsigned* bar, int round, unsigned g,
                                       unsigned rank, unsigned cnt, bool leader) {
    const unsigned tgt = (unsigned)(round + 1);
    __syncthreads();
    if (threadIdx.x < 64) {
        const int lane = threadIdx.x;
        if (leader) {
            for (;;) {
                bool ok = (lane == 0) || (lane >= (int)cnt);
                if (!ok) {
                    unsigned v = __hip_atomic_load(&bar[1024 + g * 64 + lane],
                                                   __ATOMIC_RELAXED,
                                                   __HIP_MEMORY_SCOPE_AGENT);
                    ok = (v >= tgt);
                }
                if (__all(ok)) break;
                __builtin_amdgcn_s_sleep(1);
            }
            if (lane == 0)
                __hip_atomic_store(&bar[3072 + g * 16], tgt,
                                   __ATOMIC_RELAXED, __HIP_MEMORY_SCOPE_AGENT);
        } else {
            if (lane == 0)
                __hip_atomic_store(&bar[1024 + g * 64 + rank], tgt,
                                   __ATOMIC_RELAXED, __HIP_MEMORY_SCOPE_AGENT);
        }
        while (__hip_atomic_load(&bar[3072 + g * 16], __ATOMIC_RELAXED,
                                 __HIP_MEMORY_SCOPE_AGENT) < tgt)
            __builtin_amdgcn_s_sleep(2);
        asm volatile("buffer_inv sc0\n\ts_waitcnt vmcnt(0)" ::: "memory");
    }
    __syncthreads();
}

// ---------------- prep kernels ----------------
__global__ void k_cvt(const float* __restrict__ s, _Float16* __restrict__ d, int n) {
    for (int i = blockIdx.x * blockDim.x + threadIdx.x; i < n; i += gridDim.x * blockDim.x)
        d[i] = (_Float16)s[i];
}

__global__ void k_bias(const float* a1, const float* a2, const float* b1, const float* b2,
                       const float* c1, const float* c2,
                       float* sb, float* pb, float* bb) {
    int i = blockIdx.x * blockDim.x + threadIdx.x;
    if (i < 4096) {
        sb[i] = a1[i] + a2[i];
        pb[i] = b1[i] + b2[i];
        bb[i] = c1[i] + c2[i];
    }
}

// ---------------- main persistent kernel (ROW-SPLIT + hoisted x-parts) ----------------
// XCD p owns rows {1+16p..16+16p} (p=0 also row 0). Recurrence keeps ONLY W_hh:
// LDS slice kt0..17 (147 KB/block, 4.7 MB/XCD) + streamed kt18..31 residual
// (3.6 MB/XCD, L2-resident — nothing invalidates L2 in steady state).
// x-parts hoisted into per-chunk/per-stage GEMMs (Xpre/Ppre/Bpre, fp16).
extern "C" __global__ void __launch_bounds__(NTHR, 2)
k_main(const _Float16* __restrict__ sWih, const _Float16* __restrict__ sWhh,
       const _Float16* __restrict__ pWih, const _Float16* __restrict__ pWhh,
       const _Float16* __restrict__ bWih, const _Float16* __restrict__ bWhh,
       const float* __restrict__ sb, const float* __restrict__ pb, const float* __restrict__ bb,
       const int* __restrict__ head, const int* __restrict__ body,
       const float* __restrict__ emb,
       _Float16* Xpre, _Float16* Ppre, _Float16* Bpre,
       _Float16* H, _Float16* HPL, _Float16* HPG, _Float16* HB,
       float* out, unsigned* bar)
{
    __shared__ half8 wfrag[8 * 18 * 64];   // 147.5 KB: W_hh kt 0..17, per-wave cols
    __shared__ float lds[8][16][17];       // 8.7 KB epilogue scratch
    __shared__ unsigned sMeta[4];

    const int tid  = threadIdx.x;
    const int lane = tid & 63;
    const int wv   = tid >> 6;        // 0..7
    const int l15  = lane & 15;
    const int krow = lane >> 4;       // 0..3
    const int rr   = lane >> 2;       // epilogue row 0..15
    const int mm   = lane & 3;        // epilogue unit 0..3

    // ---- census (r15-proven) ----
    {
        unsigned xcc = __builtin_amdgcn_s_getreg(XCC_ID_IMM) & 15u;
        unsigned rk = 0;
        if (tid == 0) {
            rk = __hip_atomic_fetch_add(&bar[xcc * 16], 1u,
                                        __ATOMIC_RELAXED, __HIP_MEMORY_SCOPE_AGENT);
        }
        gsync_global(bar, 256, 512, 520);
        if (tid == 0) {
            sMeta[0] = xcc;
            sMeta[1] = rk;
            sMeta[2] = __hip_atomic_load(&bar[xcc * 16], __ATOMIC_RELAXED,
                                         __HIP_MEMORY_SCOPE_AGENT);
            sMeta[3] = (rk == 0u) ? 1u : 0u;
        }
        __syncthreads();
    }
    const unsigned myG    = sMeta[0];
    const unsigned myRank = sMeta[1];
    const unsigned myCnt  = sMeta[2];
    const bool     leader = (sMeta[3] != 0u);

    const int unit = (int)myRank * 32 + wv * 4 + (l15 & 3);
    const int grow = (l15 >> 2) * HM + unit;               // gate index 0..4095
    const int uo   = (int)myRank * 32 + wv * 4 + mm;
    const int RB   = (myG == 0) ? 0 : (1 + 16 * (int)myG);
    const int NR   = (myG == 0) ? 17 : 16;                 // rows owned
    const bool two = (myG == 0);
    const int TL   = (NR * 8 + 15) >> 4;                   // Xpre tiles (8 or 9)

    const float sbi = sb[uo], sbf = sb[1024 + uo], sbg = sb[2048 + uo], sbo = sb[3072 + uo];
    const float pbi = pb[uo], pbf = pb[1024 + uo], pbg = pb[2048 + uo], pbo = pb[3072 + uo];
    const float bbi = bb[uo], bbf = bb[1024 + uo], bbg = bb[2048 + uo], bbo = bb[3072 + uo];

    // ---- stage sWhh kt 0..17 into LDS ----
#pragma unroll
    for (int kt = 0; kt < 18; ++kt)
        wfrag[(wv * 18 + kt) * 64 + lane] =
            ld8(sWhh + (size_t)grow * HM + kt * 32 + krow * 8);
    __syncthreads();

    float c0 = 0.f, c1 = 0.f, c_para = 0.f, c_body = 0.f;
    int round = 0;

    const int r0 = RB + l15;
    const int r1 = RB + 16 + l15;    // XCD0 tile1 (only row 16 valid)

    // ================= sentence LSTM: 8 chunks x (Xpre GEMM + 8 steps) =================
#pragma unroll 1
    for (int c = 0; c < 8; ++c) {
        // ---- phase B: Xpre[tc][row][4096] for this XCD's rows, t = c*8+tc ----
#pragma unroll 1
        for (int tile = 0; tile < TL; ++tile) {
            const int aL   = tile * 16 + l15;
            const bool vL  = (aL < NR * 8);
            const int ridx = vL ? (aL >> 3) : 0;
            const int tcL  = vL ? (aL & 7) : 0;
            const int row  = RB + ridx;
            const int t    = c * 8 + tcL;
            const int tok  = (row == 0) ? head[t] : body[(row - 1) * 64 + t];
            const float* Arow = emb + (size_t)tok * VD;
            f32x4 acc = {0.f, 0.f, 0.f, 0.f};
#pragma unroll 4
            for (int kt = 0; kt < 16; ++kt) {
                const int kk = kt * 32 + krow * 8;
                half8 b = ld8(sWih + (size_t)grow * VD + kk);
                half8 a = ld8_cvt(Arow + kk);
                acc = __builtin_amdgcn_mfma_f32_16x16x32_f16(a, b, acc, 0, 0, 0);
            }
#pragma unroll
            for (int q = 0; q < 4; ++q) {
                const int a2 = tile * 16 + krow * 4 + q;
                if (a2 < NR * 8) {
                    const int ridx2 = a2 >> 3, tc2 = a2 & 7;
                    Xpre[((size_t)tc2 * NROW + RB + ridx2) * 4096 + grow] =
                        (_Float16)acc[q];
                }
            }
        }
        __syncthreads();   // Xpre writes visible to this block's epilogue lanes

        // ---- phase C: 8 recurrence steps (h-part only) ----
#pragma unroll 1
        for (int tc = 0; tc < 8; ++tc) {
            const int t = c * 8 + tc;
            const _Float16* Hr = H + (size_t)(t & 1) * 144 * HM;
            _Float16*       Hw = H + (size_t)((t + 1) & 1) * 144 * HM;

            f32x4 a0 = {0.f,0.f,0.f,0.f}, a1 = {0.f,0.f,0.f,0.f};
#pragma unroll 3
            for (int kt = 0; kt < 18; ++kt) {      // LDS-resident W_hh
                const int kk = kt * 32 + krow * 8;
                half8 b = wfrag[(wv * 18 + kt) * 64 + lane];
                half8 ha = ld8(Hr + (size_t)r0 * HM + kk);
                a0 = __builtin_amdgcn_mfma_f32_16x16x32_f16(ha, b, a0, 0, 0, 0);
                if (two) {
                    half8 hb = ld8(Hr + (size_t)r1 * HM + kk);
                    a1 = __builtin_amdgcn_mfma_f32_16x16x32_f16(hb, b, a1, 0, 0, 0);
                }
            }
#pragma unroll 2
            for (int kt = 18; kt < 32; ++kt) {     // L2-resident residual
                const int kk = kt * 32 + krow * 8;
                half8 b = ld8(sWhh + (size_t)grow * HM + kk);
                half8 ha = ld8(Hr + (size_t)r0 * HM + kk);
                a0 = __builtin_amdgcn_mfma_f32_16x16x32_f16(ha, b, a0, 0, 0, 0);
                if (two) {
                    half8 hb = ld8(Hr + (size_t)r1 * HM + kk);
                    a1 = __builtin_amdgcn_mfma_f32_16x16x32_f16(hb, b, a1, 0, 0, 0);
                }
            }
            // epilogue tile0
#pragma unroll
            for (int q = 0; q < 4; ++q) lds[wv][krow * 4 + q][l15] = a0[q];
            asm volatile("s_waitcnt lgkmcnt(0)" ::: "memory");
            {
                const int row = RB + rr;
                const _Float16* xb = Xpre + ((size_t)tc * NROW + row) * 4096;
                float ip = lds[wv][rr][ 0 + mm] + (float)xb[uo]          + sbi;
                float fp = lds[wv][rr][ 4 + mm] + (float)xb[1024 + uo]   + sbf;
                float gp = lds[wv][rr][ 8 + mm] + (float)xb[2048 + uo]   + sbg;
                float op = lds[wv][rr][12 + mm] + (float)xb[3072 + uo]   + sbo;
                float h;
                lstm_cell(ip, fp, gp, op, c0, h);
                Hw[(size_t)row * HM + uo] = (_Float16)h;
                if (t == 63 && myG == 0 && rr == 0) out[1024 + uo] = h;  // r_hidden
            }
            if (two) {     // tile1: row 16 only
#pragma unroll
                for (int q = 0; q < 4; ++q) lds[wv][krow * 4 + q][l15] = a1[q];
                asm volatile("s_waitcnt lgkmcnt(0)" ::: "memory");
                if (rr == 0) {
                    const _Float16* xb = Xpre + ((size_t)tc * NROW + 16) * 4096;
                    float ip = lds[wv][0][ 0 + mm] + (float)xb[uo]        + sbi;
                    float fp = lds[wv][0][ 4 + mm] + (float)xb[1024 + uo] + sbf;
                    float gp = lds[wv][0][ 8 + mm] + (float)xb[2048 + uo] + sbg;
                    float op = lds[wv][0][12 + mm] + (float)xb[3072 + uo] + sbo;
                    float h;
                    lstm_cell(ip, fp, gp, op, c1, h);
                    Hw[(size_t)16 * HM + uo] = (_Float16)h;
                }
            }
            gsyncX(bar, round, myG, myRank, myCnt, leader); ++round;
        }
    }

    // ================= paragraph stage =================
    // restage LDS with pWhh kt 0..17 (all waves past last gsyncX => old reads done)
#pragma unroll
    for (int kt = 0; kt < 18; ++kt)
        wfrag[(wv * 18 + kt) * 64 + lane] =
            ld8(pWhh + (size_t)grow * HM + kt * 32 + krow * 8);
    // Ppre GEMM: A rows = 16 sentence encodings of this XCD's paragraph
    {
        const _Float16* Hfin = H;   // final sentence h in buffer 0
        const int arow = 1 + 16 * (int)myG + l15;     // sent_h[p=myG][s=l15]
        f32x4 acc = {0.f, 0.f, 0.f, 0.f};
#pragma unroll 4
        for (int kt = 0; kt < 32; ++kt) {
            const int kk = kt * 32 + krow * 8;
            half8 b = ld8(pWih + (size_t)grow * HM + kk);
            half8 a = ld8(Hfin + (size_t)arow * HM + kk);
            acc = __builtin_amdgcn_mfma_f32_16x16x32_f16(a, b, acc, 0, 0, 0);
        }
#pragma unroll
        for (int q = 0; q < 4; ++q) {
            const int srow = krow * 4 + q;
            Ppre[((size_t)srow * 8 + myG) * 4096 + grow] = (_Float16)acc[q];
        }
    }
    __syncthreads();

    // paragraph recurrence: 16 steps, batch 1 per XCD
    _Float16* HPl = HPL + (size_t)myG * 2 * HM;
#pragma unroll 1
    for (int s = 0; s < 16; ++s) {
        f32x4 acc = {0.f, 0.f, 0.f, 0.f};
        const _Float16* hr = HPl + (size_t)(s & 1) * HM;
#pragma unroll 3
        for (int kt = 0; kt < 18; ++kt) {
            const int kk = kt * 32 + krow * 8;
            half8 b = wfrag[(wv * 18 + kt) * 64 + lane];
            half8 a = h8z();
            if (l15 == 0) a = ld8(hr + kk);
            acc = __builtin_amdgcn_mfma_f32_16x16x32_f16(a, b, acc, 0, 0, 0);
        }
#pragma unroll 2
        for (int kt = 18; kt < 32; ++kt) {
            const int kk = kt * 32 + krow * 8;
            half8 b = ld8(pWhh + (size_t)grow * HM + kk);
            half8 a = h8z();
            if (l15 == 0) a = ld8(hr + kk);
            acc = __builtin_amdgcn_mfma_f32_16x16x32_f16(a, b, acc, 0, 0, 0);
        }
#pragma unroll
        for (int q = 0; q < 4; ++q) lds[wv][krow * 4 + q][l15] = acc[q];
        asm volatile("s_waitcnt lgkmcnt(0)" ::: "memory");
        if (rr == 0) {
            const _Float16* xb = Ppre + ((size_t)s * 8 + myG) * 4096;
            float ip = lds[wv][0][ 0 + mm] + (float)xb[uo]        + pbi;
            float fp = lds[wv][0][ 4 + mm] + (float)xb[1024 + uo] + pbf;
            float gp = lds[wv][0][ 8 + mm] + (float)xb[2048 + uo] + pbg;
            float op = lds[wv][0][12 + mm] + (float)xb[3072 + uo] + pbo;
            float h;
            lstm_cell(ip, fp, gp, op, c_para, h);
            HPl[(size_t)((s + 1) & 1) * HM + uo] = (_Float16)h;
            if (s == 15) HPG[(size_t)myG * HM + uo] = (_Float16)h;
        }
        gsyncX(bar, round, myG, myRank, myCnt, leader); ++round;
    }

    // ---- global handoff: all XCDs' h_para -> L3 -> XCD 0 (r5-proven) ----
    gsync_global(bar, 3584, 3840, 3848);
    if (myG != 0) return;

    // ================= body stage (XCD 0) =================
#pragma unroll
    for (int kt = 0; kt < 18; ++kt)
        wfrag[(wv * 18 + kt) * 64 + lane] =
            ld8(bWhh + (size_t)grow * HM + kt * 32 + krow * 8);
    // Bpre GEMM: A rows = 8 paragraph encodings
    {
        f32x4 acc = {0.f, 0.f, 0.f, 0.f};
#pragma unroll 4
        for (int kt = 0; kt < 32; ++kt) {
            const int kk = kt * 32 + krow * 8;
            half8 b = ld8(bWih + (size_t)grow * HM + kk);
            half8 a = h8z();
            if (l15 < 8) a = ld8(HPG + (size_t)l15 * HM + kk);
            acc = __builtin_amdgcn_mfma_f32_16x16x32_f16(a, b, acc, 0, 0, 0);
        }
#pragma unroll
        for (int q = 0; q < 4; ++q) {
            const int brow = krow * 4 + q;
            if (brow < 8)
                Bpre[(size_t)brow * 4096 + grow] = (_Float16)acc[q];
        }
    }
    __syncthreads();

    // body recurrence: 8 steps, batch 1
#pragma unroll 1
    for (int t = 0; t < 8; ++t) {
        f32x4 acc = {0.f, 0.f, 0.f, 0.f};
        const _Float16* hr = HB + (size_t)(t & 1) * HM;
#pragma unroll 3
        for (int kt = 0; kt < 18; ++kt) {
            const int kk = kt * 32 + krow * 8;
            half8 b = wfrag[(wv * 18 + kt) * 64 + lane];
            half8 a = h8z();
            if (l15 == 0) a = ld8(hr + kk);
            acc = __builtin_amdgcn_mfma_f32_16x16x32_f16(a, b, acc, 0, 0, 0);
        }
#pragma unroll 2
        for (int kt = 18; kt < 32; ++kt) {
            const int kk = kt * 32 + krow * 8;
            half8 b = ld8(bWhh + (size_t)grow * HM + kk);
            half8 a = h8z();
            if (l15 == 0) a = ld8(hr + kk);
            acc = __builtin_amdgcn_mfma_f32_16x16x32_f16(a, b, acc, 0, 0, 0);
        }
#pragma unroll
        for (int q = 0; q < 4; ++q) lds[wv][krow * 4 + q][l15] = acc[q];
        asm volatile("s_waitcnt lgkmcnt(0)" ::: "memory");
        if (rr == 0) {
            const _Float16* xb = Bpre + (size_t)t * 4096;
            float ip = lds[wv][0][ 0 + mm] + (float)xb[uo]        + bbi;
            float fp = lds[wv][0][ 4 + mm] + (float)xb[1024 + uo] + bbf;
            float gp = lds[wv][0][ 8 + mm] + (float)xb[2048 + uo] + bbg;
            float op = lds[wv][0][12 + mm] + (float)xb[3072 + uo] + bbo;
            float h;
            lstm_cell(ip, fp, gp, op, c_body, h);
            HB[(size_t)((t + 1) & 1) * HM + uo] = (_Float16)h;
            if (t == 7) out[uo] = h;               // h_body
        }
        gsyncX(bar, round, myG, myRank, myCnt, leader); ++round;
    }
}

// ---------------- host ----------------
extern "C" void kernel_launch(void* const* d_in, const int* in_sizes, int n_in,
                              void* d_out, int out_size, void* d_ws, size_t ws_size,
                              hipStream_t stream) {
    const int*   head  = (const int*)d_in[0];
    const int*   body  = (const int*)d_in[1];
    const float* emb   = (const float*)d_in[2];
    const float* sWihF = (const float*)d_in[3];
    const float* sWhhF = (const float*)d_in[4];
    const float* sbih  = (const float*)d_in[5];
    const float* sbhh  = (const float*)d_in[6];
    const float* pWihF = (const float*)d_in[7];
    const float* pWhhF = (const float*)d_in[8];
    const float* pbih  = (const float*)d_in[9];
    const float* pbhh  = (const float*)d_in[10];
    const float* bWihF = (const float*)d_in[11];
    const float* bWhhF = (const float*)d_in[12];
    const float* bbih  = (const float*)d_in[13];
    const float* bbhh  = (const float*)d_in[14];

    char* ws = (char*)d_ws;
    _Float16* sWih16 = (_Float16*)(ws + OFF_SWIH);
    _Float16* sWhh16 = (_Float16*)(ws + OFF_SWHH);
    _Float16* pWih16 = (_Float16*)(ws + OFF_PWIH);
    _Float16* pWhh16 = (_Float16*)(ws + OFF_PWHH);
    _Float16* bWih16 = (_Float16*)(ws + OFF_BWIH);
    _Float16* bWhh16 = (_Float16*)(ws + OFF_BWHH);
    float*    sbp    = (float*)(ws + OFF_SB);
    float*    pbp    = (float*)(ws + OFF_PB);
    float*    bbp    = (float*)(ws + OFF_BB);
    _Float16* Xprep  = (_Float16*)(ws + OFF_XPRE);
    _Float16* Pprep  = (_Float16*)(ws + OFF_PPRE);
    _Float16* Bprep  = (_Float16*)(ws + OFF_BPRE);
    _Float16* Hp     = (_Float16*)(ws + OFF_H);
    _Float16* HPLp   = (_Float16*)(ws + OFF_HPL);
    _Float16* HPGp   = (_Float16*)(ws + OFF_HPG);
    _Float16* HBp    = (_Float16*)(ws + OFF_HB);
    unsigned* barp   = (unsigned*)(ws + OFF_BAR);
    float*    outp   = (float*)d_out;

    hipMemsetAsync(ws + OFF_STATE, 0, STATE_BYTES, stream);
    k_cvt<<<512, 256, 0, stream>>>(sWihF, sWih16, 4096 * 512);
    k_cvt<<<1024, 256, 0, stream>>>(sWhhF, sWhh16, 4096 * 1024);
    k_cvt<<<1024, 256, 0, stream>>>(pWihF, pWih16, 4096 * 1024);
    k_cvt<<<1024, 256, 0, stream>>>(pWhhF, pWhh16, 4096 * 1024);
    k_cvt<<<1024, 256, 0, stream>>>(bWihF, bWih16, 4096 * 1024);
    k_cvt<<<1024, 256, 0, stream>>>(bWhhF, bWhh16, 4096 * 1024);
    k_bias<<<16, 256, 0, stream>>>(sbih, sbhh, pbih, pbhh, bbih, bbhh, sbp, pbp, bbp);

    void* args[] = { &sWih16, &sWhh16, &pWih16, &pWhh16, &bWih16, &bWhh16,
                     &sbp, &pbp, &bbp,
                     &head, &body, &emb,
                     &Xprep, &Pprep, &Bprep,
                     &Hp, &HPLp, &HPGp, &HBp, &outp, &barp };
    hipError_t err = hipLaunchCooperativeKernel(reinterpret_cast<void*>(k_main),
                                                dim3(NBLK), dim3(NTHR), args, 0, stream);
    if (err != hipSuccess) {
        k_main<<<NBLK, NTHR, 0, stream>>>(sWih16, sWhh16, pWih16, pWhh16, bWih16, bWhh16,
                                          sbp, pbp, bbp, head, body, emb,
                                          Xprep, Pprep, Bprep,
                                          Hp, HPLp, HPGp, HBp, outp, barp);
    }
}

// Round 17
// 1677.272 us; speedup vs baseline: 1.7187x; 1.4705x over previous
//
#include <hip/hip_runtime.h>

typedef _Float16 half8 __attribute__((ext_vector_type(8)));
typedef float f32x4 __attribute__((ext_vector_type(4)));

#define NBLK 256
#define NTHR 512
#define VD   512
#define HM   1024
#define MPAD 144
#define NROW 129

// HW_REG_XCC_ID (id=20, offset=0, size=4)
#define XCC_ID_IMM 6164

// ---------------- workspace layout (~62.7 MB) ----------------
static constexpr size_t SZ_SWIH = (size_t)4096 * 512 * 2;
static constexpr size_t SZ_W1K  = (size_t)4096 * 1024 * 2;
static constexpr size_t OFF_SWIH = 0;
static constexpr size_t OFF_SWHH = OFF_SWIH + SZ_SWIH;
static constexpr size_t OFF_PWIH = OFF_SWHH + SZ_W1K;
static constexpr size_t OFF_PWHH = OFF_PWIH + SZ_W1K;
static constexpr size_t OFF_BWIH = OFF_PWHH + SZ_W1K;
static constexpr size_t OFF_BWHH = OFF_BWIH + SZ_W1K;
static constexpr size_t OFF_SB   = OFF_BWHH + SZ_W1K;
static constexpr size_t OFF_PB   = OFF_SB + (size_t)4096 * 4;
static constexpr size_t OFF_BB   = OFF_PB + (size_t)4096 * 4;
static constexpr size_t OFF_X16  = OFF_BB + (size_t)4096 * 4;
static constexpr size_t SZ_X16   = (size_t)64 * MPAD * VD * 2;          // 9.4 MB
static constexpr size_t OFF_XPRE = OFF_X16 + SZ_X16;                    // [8][129][4096] f16
static constexpr size_t SZ_XPRE  = (size_t)8 * NROW * 4096 * 2;         // 8.45 MB
static constexpr size_t OFF_STATE = OFF_XPRE + SZ_XPRE;
static constexpr size_t OFF_H    = OFF_STATE;               // [2][144][1024] f16
static constexpr size_t SZ_H     = (size_t)2 * MPAD * HM * 2;
static constexpr size_t OFF_HP   = OFF_H + SZ_H;            // [17][8][1024] f16
static constexpr size_t SZ_HP    = (size_t)17 * 8 * HM * 2;
static constexpr size_t OFF_HB   = OFF_HP + SZ_HP;          // [9][1024] f16
static constexpr size_t SZ_HB    = (size_t)9 * HM * 2;
static constexpr size_t OFF_BAR  = OFF_HB + SZ_HB;          // barrier counters (16 KB)
static constexpr size_t STATE_BYTES = (OFF_BAR + 16384) - OFF_STATE;

// bar[] (uint32 idx), all accessed sc1/agent (L3-resident):
//   census cen[g]=bar[g*16] (g<16); census barrier csub[i]=bar[256+i*16],
//   cmaster=bar[512], cgen=bar[520];
//   per-step local arrival slots: bar[1024 + g*64 + rank] (g<16, rank<64);
//   per-step global done-flags:   bar[3072 + g*16]        (64B apart).

// ---------------- helpers ----------------
__device__ __forceinline__ half8 h8z() {
    half8 z = {(_Float16)0,(_Float16)0,(_Float16)0,(_Float16)0,
               (_Float16)0,(_Float16)0,(_Float16)0,(_Float16)0};
    return z;
}

__device__ __forceinline__ half8 ld8(const _Float16* p) {
    return *reinterpret_cast<const half8*>(p);
}

__device__ __forceinline__ void lstm_cell(float ip, float fp, float gp, float op,
                                          float& c, float& h) {
    float ig = 1.0f / (1.0f + expf(-ip));
    float fg = 1.0f / (1.0f + expf(-fp));
    float og = 1.0f / (1.0f + expf(-op));
    float gv = tanhf(gp);
    c = fg * c + ig * gv;
    h = og * tanhf(c);
}

// One-shot census barrier: r5/r6-PROVEN full-threadfence barrier, own counters.
__device__ __forceinline__ void gsync_census(unsigned* bar) {
    __syncthreads();
    if (threadIdx.x == 0) {
        __threadfence();
        unsigned a = __hip_atomic_fetch_add(&bar[256 + (blockIdx.x & 15) * 16], 1u,
                                            __ATOMIC_RELAXED, __HIP_MEMORY_SCOPE_AGENT);
        if (a == 15u) {
            unsigned m = __hip_atomic_fetch_add(&bar[512], 1u,
                                                __ATOMIC_RELAXED, __HIP_MEMORY_SCOPE_AGENT);
            if (m == 15u)
                __hip_atomic_store(&bar[520], 1u,
                                   __ATOMIC_RELAXED, __HIP_MEMORY_SCOPE_AGENT);
        }
        while (__hip_atomic_load(&bar[520], __ATOMIC_RELAXED,
                                 __HIP_MEMORY_SCOPE_AGENT) < 1u)
            __builtin_amdgcn_s_sleep(2);
        __threadfence();
    }
    __syncthreads();
}

// Per-step barrier (r9-PROVEN gsync5, verbatim): parallel slot arrival +
// wave-parallel polls; per-XCD leader runs the full __threadfence (wbl2+inv)
// then sets its done-flag; all blocks wave-poll the 8 done-flags.
__device__ __forceinline__ void gsync5(unsigned* bar, int round, unsigned g,
                                       unsigned rank, unsigned cnt,
                                       bool leader, bool gAct) {
    const unsigned tgt = (unsigned)(round + 1);
    __syncthreads();
    if (threadIdx.x < 64) {
        const int lane = threadIdx.x;
        if (leader) {
            for (;;) {
                bool ok = (lane == 0) || (lane >= (int)cnt);
                if (!ok) {
                    unsigned v = __hip_atomic_load(&bar[1024 + g * 64 + lane],
                                                   __ATOMIC_RELAXED,
                                                   __HIP_MEMORY_SCOPE_AGENT);
                    ok = (v >= tgt);
                }
                if (__all(ok)) break;
                __builtin_amdgcn_s_sleep(1);
            }
            __threadfence();               // wbl2+inv: whole XCD's h -> L3, completed
            if (lane == 0)
                __hip_atomic_store(&bar[3072 + g * 16], tgt,
                                   __ATOMIC_RELAXED, __HIP_MEMORY_SCOPE_AGENT);
        } else {
            if (lane == 0)
                __hip_atomic_store(&bar[1024 + g * 64 + rank], tgt,
                                   __ATOMIC_RELAXED, __HIP_MEMORY_SCOPE_AGENT);
        }
        for (;;) {
            bool ok = true;
            if (gAct) {
                unsigned v = __hip_atomic_load(&bar[3072 + lane * 16],
                                               __ATOMIC_RELAXED,
                                               __HIP_MEMORY_SCOPE_AGENT);
                ok = (v >= tgt);
            }
            if (__all(ok)) break;
            __builtin_amdgcn_s_sleep(2);
        }
        asm volatile("buffer_inv sc0\n\ts_waitcnt vmcnt(0)" ::: "memory");
    }
    __syncthreads();
}

// ---------------- prep kernels ----------------
__global__ void k_cvt(const float* __restrict__ s, _Float16* __restrict__ d, int n) {
    for (int i = blockIdx.x * blockDim.x + threadIdx.x; i < n; i += gridDim.x * blockDim.x)
        d[i] = (_Float16)s[i];
}

__global__ void k_bias(const float* a1, const float* a2, const float* b1, const float* b2,
                       const float* c1, const float* c2,
                       float* sb, float* pb, float* bb) {
    int i = blockIdx.x * blockDim.x + threadIdx.x;
    if (i < 4096) {
        sb[i] = a1[i] + a2[i];
        pb[i] = b1[i] + b2[i];
        bb[i] = c1[i] + c2[i];
    }
}

// X16[t][row][d]; row 0 = headline, rows 1..128 = body sentences, 129..143 zero pad
__global__ void k_gather(const int* __restrict__ head, const int* __restrict__ body,
                         const float* __restrict__ emb, _Float16* __restrict__ X16) {
    const int total = 64 * MPAD * VD;
    for (int idx = blockIdx.x * blockDim.x + threadIdx.x; idx < total;
         idx += gridDim.x * blockDim.x) {
        int d   = idx & (VD - 1);
        int rt  = idx >> 9;
        int row = rt % MPAD;
        int t   = rt / MPAD;
        float v = 0.0f;
        if (row == 0)         v = emb[(size_t)head[t] * VD + d];
        else if (row < NROW)  v = emb[(size_t)body[(row - 1) * 64 + t] * VD + d];
        X16[idx] = (_Float16)v;
    }
}

// ---------------- main persistent kernel (r9 base + hoisted x-part) ----------------
// 256 blocks x 512 thr (8 waves). Block owns 4 hidden units (16 gate cols).
// Sentence: per 8-step chunk, wave wv first computes Xpre[t=c*8+wv][129][its 16
// gate cols] (block-local produce+consume: no new sync). Steps then run the
// h-recurrence only (K=1024, sWhh fully LDS-resident, 32 KB); waves g=wv&3 own
// row-tiles {g, g+4, (g==0: 8)}; kh=wv>>2 takes k-tiles kh*16..kh*16+15.
// Para/body stages: r9 verbatim.
extern "C" __global__ void __launch_bounds__(NTHR, 2)
k_main(const _Float16* __restrict__ sWih, const _Float16* __restrict__ sWhh,
       const _Float16* __restrict__ pWih, const _Float16* __restrict__ pWhh,
       const _Float16* __restrict__ bWih, const _Float16* __restrict__ bWhh,
       const float* __restrict__ sb, const float* __restrict__ pb, const float* __restrict__ bb,
       const _Float16* __restrict__ X16, _Float16* Xpre,
       _Float16* H, _Float16* HP, _Float16* HB,
       float* out, unsigned* bar)
{
    __shared__ float lds[8][3][16][17];
    __shared__ half8 wfrag[4096];     // 64 KB: B-fragments for the current stage
    __shared__ unsigned sMeta[4];

    const int tid  = threadIdx.x;
    const int lane = tid & 63;
    const int wv   = tid >> 6;        // 0..7
    const int g    = wv & 3;
    const int kh   = wv >> 2;         // K-half
    const int l15  = lane & 15;
    const int krow = lane >> 4;       // 0..3
    const int rr   = lane >> 2;       // epilogue row 0..15
    const int mm   = lane & 3;        // epilogue col 0..3
    const int ubase = blockIdx.x * 4;
    const int uo    = ubase + mm;
    const int grow  = (l15 >> 2) * HM + ubase + (l15 & 3);  // weight row for B col l15

    const float sbi = sb[uo], sbf = sb[1024 + uo], sbg = sb[2048 + uo], sbo = sb[3072 + uo];
    const float pbi = pb[uo], pbf = pb[1024 + uo], pbg = pb[2048 + uo], pbo = pb[3072 + uo];
    const float bbi = bb[uo], bbf = bb[1024 + uo], bbg = bb[2048 + uo], bbo = bb[3072 + uo];

    const int rA0 = g * 16 + l15;     // tile g
    const int rA1 = rA0 + 64;         // tile g+4
    const int rA2 = 128 + l15;        // tile 8 (g==0 waves)

    float c_main = 0.f, c_t8 = 0.f, c_para = 0.f, c_body = 0.f, rhid_reg = 0.f;
    int round = 0;

    // ---- census (r9-proven) + stage sWhh kt 0..31 into LDS ----
    {
        unsigned xcc = __builtin_amdgcn_s_getreg(XCC_ID_IMM) & 15u;
        unsigned rk = 0;
        if (tid == 0) {
            rk = __hip_atomic_fetch_add(&bar[xcc * 16], 1u,
                                        __ATOMIC_RELAXED, __HIP_MEMORY_SCOPE_AGENT);
        }
#pragma unroll
        for (int q = 0; q < 4; ++q) {
            int kt = wv + q * 8;
            wfrag[kt * 64 + lane] = ld8(sWhh + (size_t)grow * HM + kt * 32 + krow * 8);
        }
        gsync_census(bar);
        if (tid == 0) {
            sMeta[0] = xcc;
            sMeta[1] = rk;
            sMeta[2] = __hip_atomic_load(&bar[xcc * 16], __ATOMIC_RELAXED,
                                         __HIP_MEMORY_SCOPE_AGENT);
            sMeta[3] = (rk == 0u) ? 1u : 0u;
        }
        __syncthreads();
    }
    const unsigned myG    = sMeta[0];
    const unsigned myRank = sMeta[1];
    const unsigned myCnt  = sMeta[2];
    const bool     leader = (sMeta[3] != 0u);
    bool gAct = false;
    if (tid < 16) {
        gAct = (__hip_atomic_load(&bar[tid * 16], __ATOMIC_RELAXED,
                                  __HIP_MEMORY_SCOPE_AGENT) != 0u);
    }

    // ---- hoist sWih B-fragments for the Xpre GEMM (16 regs) ----
    half8 wb[16];
#pragma unroll
    for (int kt = 0; kt < 16; ++kt)
        wb[kt] = ld8(sWih + (size_t)grow * VD + kt * 32 + krow * 8);

    // ================= sentence: 8 chunks x (Xpre GEMM + 8 steps) =================
#pragma unroll 1
    for (int c = 0; c < 8; ++c) {
        // ---- Xpre GEMM: wave wv computes t = c*8 + wv, all 129 rows, 16 cols ----
        {
            const int t = c * 8 + wv;
            const _Float16* Xt = X16 + (size_t)t * MPAD * VD;
#pragma unroll 1
            for (int tile = 0; tile < 9; ++tile) {
                const int arow = tile * 16 + l15;        // 0..143 (pad rows zeroed)
                const _Float16* Arow = Xt + (size_t)arow * VD;
                f32x4 acc = {0.f, 0.f, 0.f, 0.f};
#pragma unroll 4
                for (int kt = 0; kt < 16; ++kt) {
                    half8 a = ld8(Arow + kt * 32 + krow * 8);
                    acc = __builtin_amdgcn_mfma_f32_16x16x32_f16(a, wb[kt], acc, 0, 0, 0);
                }
#pragma unroll
                for (int q = 0; q < 4; ++q) {
                    const int row2 = tile * 16 + krow * 4 + q;
                    if (row2 < NROW)
                        Xpre[((size_t)wv * NROW + row2) * 4096 + grow] = (_Float16)acc[q];
                }
            }
        }
        __syncthreads();   // Xpre visible block-wide (same CU, L1-coherent)

        // ---- 8 recurrence steps (h-part only, K=1024 from LDS) ----
#pragma unroll 1
        for (int tc = 0; tc < 8; ++tc) {
            const int t = c * 8 + tc;
            const _Float16* Hr = H + (size_t)(t & 1) * MPAD * HM;
            _Float16*       Hw = H + (size_t)((t + 1) & 1) * MPAD * HM;

            f32x4 a0 = {0.f,0.f,0.f,0.f}, a1 = {0.f,0.f,0.f,0.f}, a2 = {0.f,0.f,0.f,0.f};
            const int kb = kh * 16;
#pragma unroll 4
            for (int kt = 0; kt < 16; ++kt) {
                const int kk = (kb + kt) * 32 + krow * 8;
                half8 b  = wfrag[(kb + kt) * 64 + lane];
                half8 h0 = ld8(Hr + (size_t)rA0 * HM + kk);
                half8 h1 = ld8(Hr + (size_t)rA1 * HM + kk);
                a0 = __builtin_amdgcn_mfma_f32_16x16x32_f16(h0, b, a0, 0, 0, 0);
                a1 = __builtin_amdgcn_mfma_f32_16x16x32_f16(h1, b, a1, 0, 0, 0);
                if (g == 0) {
                    half8 h2 = ld8(Hr + (size_t)rA2 * HM + kk);
                    a2 = __builtin_amdgcn_mfma_f32_16x16x32_f16(h2, b, a2, 0, 0, 0);
                }
            }
            // stash K-half partials
#pragma unroll
            for (int q = 0; q < 4; ++q) {
                lds[wv][0][krow * 4 + q][l15] = a0[q];
                lds[wv][1][krow * 4 + q][l15] = a1[q];
            }
            if (g == 0) {
#pragma unroll
                for (int q = 0; q < 4; ++q) lds[wv][2][krow * 4 + q][l15] = a2[q];
            }
            __syncthreads();
            // epilogue: wave T reduces the two K-half partials of tile T
            {
                const int T  = wv;
                const int wA = (T < 4) ? T     : T - 4;
                const int wB = (T < 4) ? T + 4 : T;
                const int jj = (T < 4) ? 0 : 1;
                const int rowg = T * 16 + rr;
                if (rowg < NROW) {
                    const _Float16* xb = Xpre + ((size_t)tc * NROW + rowg) * 4096;
                    float ip = lds[wA][jj][rr][ 0 + mm] + lds[wB][jj][rr][ 0 + mm]
                             + (float)xb[uo]        + sbi;
                    float fp = lds[wA][jj][rr][ 4 + mm] + lds[wB][jj][rr][ 4 + mm]
                             + (float)xb[1024 + uo] + sbf;
                    float gp = lds[wA][jj][rr][ 8 + mm] + lds[wB][jj][rr][ 8 + mm]
                             + (float)xb[2048 + uo] + sbg;
                    float op = lds[wA][jj][rr][12 + mm] + lds[wB][jj][rr][12 + mm]
                             + (float)xb[3072 + uo] + sbo;
                    float h;
                    lstm_cell(ip, fp, gp, op, c_main, h);
                    if (t == 63 && wv == 0 && rr == 0) rhid_reg = h;
                    Hw[(size_t)rowg * HM + uo] = (_Float16)h;
                }
            }
            if (wv == 0) {   // tile 8: only row 128 valid
                const int rowg = 128 + rr;
                if (rowg < NROW) {
                    const _Float16* xb = Xpre + ((size_t)tc * NROW + rowg) * 4096;
                    float ip = lds[0][2][rr][ 0 + mm] + lds[4][2][rr][ 0 + mm]
                             + (float)xb[uo]        + sbi;
                    float fp = lds[0][2][rr][ 4 + mm] + lds[4][2][rr][ 4 + mm]
                             + (float)xb[1024 + uo] + sbf;
                    float gp = lds[0][2][rr][ 8 + mm] + lds[4][2][rr][ 8 + mm]
                             + (float)xb[2048 + uo] + sbg;
                    float op = lds[0][2][rr][12 + mm] + lds[4][2][rr][12 + mm]
                             + (float)xb[3072 + uo] + sbo;
                    float h;
                    lstm_cell(ip, fp, gp, op, c_t8, h);
                    Hw[(size_t)rowg * HM + uo] = (_Float16)h;
                }
            }
            gsync5(bar, round, myG, myRank, myCnt, leader, gAct); ++round;
        }
    }

    // ---- stage paragraph-stage weights: ih kt0..31 -> slot kt, hh -> slot 32+kt ----
#pragma unroll
    for (int q = 0; q < 4; ++q) {
        int kt = wv + q * 8;
        wfrag[kt * 64 + lane]        = ld8(pWih + (size_t)grow * HM + kt * 32 + krow * 8);
        wfrag[(32 + kt) * 64 + lane] = ld8(pWhh + (size_t)grow * HM + kt * 32 + krow * 8);
    }
    __syncthreads();

    // ================= paragraph LSTM: 16 steps, batch 8 (pad 16) =================
    const _Float16* Hs = H;   // sentence-final h landed in buffer 0
#pragma unroll 1
    for (int s = 0; s < 16; ++s) {
        const _Float16* HPr = HP + (size_t)s * 8 * HM;
        _Float16*       HPw = HP + (size_t)(s + 1) * 8 * HM;
        f32x4 acc = {0.f,0.f,0.f,0.f};
        if (wv < 4) {
            const int rs = 1 + l15 * 16 + s;                  // sent_h[p=l15][s]
#pragma unroll
            for (int k = 0; k < 8; ++k) {
                const int kt = wv * 8 + k;
                const int kk = kt * 32 + krow * 8;
                half8 b = wfrag[kt * 64 + lane];
                half8 a = h8z();
                if (l15 < 8) a = ld8(Hs + (size_t)rs * HM + kk);
                acc = __builtin_amdgcn_mfma_f32_16x16x32_f16(a, b, acc, 0, 0, 0);
            }
        } else {
#pragma unroll
            for (int k = 0; k < 8; ++k) {
                const int kt = (wv - 4) * 8 + k;
                const int kk = kt * 32 + krow * 8;
                half8 b = wfrag[(32 + kt) * 64 + lane];
                half8 a = h8z();
                if (l15 < 8) a = ld8(HPr + (size_t)l15 * HM + kk);
                acc = __builtin_amdgcn_mfma_f32_16x16x32_f16(a, b, acc, 0, 0, 0);
            }
        }
#pragma unroll
        for (int q = 0; q < 4; ++q) lds[wv][0][krow * 4 + q][l15] = acc[q];
        __syncthreads();
        if (wv == 0 && rr < 8) {
            float ip = pbi, fp = pbf, gp = pbg, op = pbo;
#pragma unroll
            for (int w = 0; w < 8; ++w) {
                ip += lds[w][0][rr][ 0 + mm];
                fp += lds[w][0][rr][ 4 + mm];
                gp += lds[w][0][rr][ 8 + mm];
                op += lds[w][0][rr][12 + mm];
            }
            float h;
            lstm_cell(ip, fp, gp, op, c_para, h);
            HPw[(size_t)rr * HM + uo] = (_Float16)h;
        }
        gsync5(bar, round, myG, myRank, myCnt, leader, gAct); ++round;
    }

    // ---- stage body-stage weights (same slot scheme) ----
#pragma unroll
    for (int q = 0; q < 4; ++q) {
        int kt = wv + q * 8;
        wfrag[kt * 64 + lane]        = ld8(bWih + (size_t)grow * HM + kt * 32 + krow * 8);
        wfrag[(32 + kt) * 64 + lane] = ld8(bWhh + (size_t)grow * HM + kt * 32 + krow * 8);
    }
    __syncthreads();

    // ================= body LSTM: 8 steps, batch 1 =================
    const _Float16* HPf = HP + (size_t)16 * 8 * HM;   // para-final h
#pragma unroll 1
    for (int t = 0; t < 8; ++t) {
        const _Float16* HBr = HB + (size_t)t * HM;
        _Float16*       HBw = HB + (size_t)(t + 1) * HM;
        f32x4 acc = {0.f,0.f,0.f,0.f};
        if (wv < 4) {
#pragma unroll
            for (int k = 0; k < 8; ++k) {
                const int kt = wv * 8 + k;
                const int kk = kt * 32 + krow * 8;
                half8 b = wfrag[kt * 64 + lane];
                half8 a = h8z();
                if (l15 == 0) a = ld8(HPf + (size_t)t * HM + kk);
                acc = __builtin_amdgcn_mfma_f32_16x16x32_f16(a, b, acc, 0, 0, 0);
            }
        } else {
#pragma unroll
            for (int k = 0; k < 8; ++k) {
                const int kt = (wv - 4) * 8 + k;
                const int kk = kt * 32 + krow * 8;
                half8 b = wfrag[(32 + kt) * 64 + lane];
                half8 a = h8z();
                if (l15 == 0) a = ld8(HBr + kk);
                acc = __builtin_amdgcn_mfma_f32_16x16x32_f16(a, b, acc, 0, 0, 0);
            }
        }
#pragma unroll
        for (int q = 0; q < 4; ++q) lds[wv][0][krow * 4 + q][l15] = acc[q];
        __syncthreads();
        if (wv == 0 && rr == 0) {   // lanes 0..3
            float ip = bbi, fp = bbf, gp = bbg, op = bbo;
#pragma unroll
            for (int w = 0; w < 8; ++w) {
                ip += lds[w][0][0][ 0 + mm];
                fp += lds[w][0][0][ 4 + mm];
                gp += lds[w][0][0][ 8 + mm];
                op += lds[w][0][0][12 + mm];
            }
            float h;
            lstm_cell(ip, fp, gp, op, c_body, h);
            HBw[uo] = (_Float16)h;
            if (t == 7) {
                out[uo]        = h;          // h_body
                out[1024 + uo] = rhid_reg;   // r_hidden
            }
        }
        gsync5(bar, round, myG, myRank, myCnt, leader, gAct); ++round;
    }
}

// ---------------- host ----------------
extern "C" void kernel_launch(void* const* d_in, const int* in_sizes, int n_in,
                              void* d_out, int out_size, void* d_ws, size_t ws_size,
                              hipStream_t stream) {
    const int*   head  = (const int*)d_in[0];
    const int*   body  = (const int*)d_in[1];
    const float* emb   = (const float*)d_in[2];
    const float* sWihF = (const float*)d_in[3];
    const float* sWhhF = (const float*)d_in[4];
    const float* sbih  = (const float*)d_in[5];
    const float* sbhh  = (const float*)d_in[6];
    const float* pWihF = (const float*)d_in[7];
    const float* pWhhF = (const float*)d_in[8];
    const float* pbih  = (const float*)d_in[9];
    const float* pbhh  = (const float*)d_in[10];
    const float* bWihF = (const float*)d_in[11];
    const float* bWhhF = (const float*)d_in[12];
    const float* bbih  = (const float*)d_in[13];
    const float* bbhh  = (const float*)d_in[14];

    char* ws = (char*)d_ws;
    _Float16* sWih16 = (_Float16*)(ws + OFF_SWIH);
    _Float16* sWhh16 = (_Float16*)(ws + OFF_SWHH);
    _Float16* pWih16 = (_Float16*)(ws + OFF_PWIH);
    _Float16* pWhh16 = (_Float16*)(ws + OFF_PWHH);
    _Float16* bWih16 = (_Float16*)(ws + OFF_BWIH);
    _Float16* bWhh16 = (_Float16*)(ws + OFF_BWHH);
    float*    sbp    = (float*)(ws + OFF_SB);
    float*    pbp    = (float*)(ws + OFF_PB);
    float*    bbp    = (float*)(ws + OFF_BB);
    _Float16* X16    = (_Float16*)(ws + OFF_X16);
    _Float16* Xprep  = (_Float16*)(ws + OFF_XPRE);
    _Float16* Hp     = (_Float16*)(ws + OFF_H);
    _Float16* HPp    = (_Float16*)(ws + OFF_HP);
    _Float16* HBp    = (_Float16*)(ws + OFF_HB);
    unsigned* barp   = (unsigned*)(ws + OFF_BAR);
    float*    outp   = (float*)d_out;

    hipMemsetAsync(ws + OFF_STATE, 0, STATE_BYTES, stream);
    k_cvt<<<512, 256, 0, stream>>>(sWihF, sWih16, 4096 * 512);
    k_cvt<<<1024, 256, 0, stream>>>(sWhhF, sWhh16, 4096 * 1024);
    k_cvt<<<1024, 256, 0, stream>>>(pWihF, pWih16, 4096 * 1024);
    k_cvt<<<1024, 256, 0, stream>>>(pWhhF, pWhh16, 4096 * 1024);
    k_cvt<<<1024, 256, 0, stream>>>(bWihF, bWih16, 4096 * 1024);
    k_cvt<<<1024, 256, 0, stream>>>(bWhhF, bWhh16, 4096 * 1024);
    k_bias<<<16, 256, 0, stream>>>(sbih, sbhh, pbih, pbhh, bbih, bbhh, sbp, pbp, bbp);
    k_gather<<<2048, 256, 0, stream>>>(head, body, emb, X16);

    void* args[] = { &sWih16, &sWhh16, &pWih16, &pWhh16, &bWih16, &bWhh16,
                     &sbp, &pbp, &bbp, &X16, &Xprep,
                     &Hp, &HPp, &HBp, &outp, &barp };
    hipError_t err = hipLaunchCooperativeKernel(reinterpret_cast<void*>(k_main),
                                                dim3(NBLK), dim3(NTHR), args, 0, stream);
    if (err != hipSuccess) {
        k_main<<<NBLK, NTHR, 0, stream>>>(sWih16, sWhh16, pWih16, pWhh16, bWih16, bWhh16,
                                          sbp, pbp, bbp, X16, Xprep,
                                          Hp, HPp, HBp, outp, barp);
    }
}